// Round 1
// baseline (7842.356 us; speedup 1.0000x reference)
//
#include <hip/hip_runtime.h>
#include <math.h>

#define Hdim 128
#define Fdim 32
#define Tdim 16

__device__ __forceinline__ float sigf(float x) {
    return 1.0f / (1.0f + __expf(-x));
}
__device__ __forceinline__ float tanh_fast(float x) {
    x = fminf(fmaxf(x, -15.f), 15.f);
    float e = __expf(2.f * x);
    return (e - 1.f) / (e + 1.f);
}

// ---------------- x (N,F,T) -> xs (T,N,F) ----------------
__global__ __launch_bounds__(256)
void transpose_x_kernel(const float* __restrict__ x, float* __restrict__ xs, int nf) {
    int tid = blockIdx.x * 256 + threadIdx.x;  // over N*F
    if (tid >= nf) return;
    const float4* src = reinterpret_cast<const float4*>(x + (size_t)tid * Tdim);
    float4 a = src[0], b = src[1], c = src[2], d = src[3];
    float v[16] = {a.x,a.y,a.z,a.w, b.x,b.y,b.z,b.w, c.x,c.y,c.z,c.w, d.x,d.y,d.z,d.w};
    #pragma unroll
    for (int t = 0; t < Tdim; ++t) xs[(size_t)t * nf + tid] = v[t];
}

// ---------------- fused LSTM step ----------------
// z = xt @ Wih^T + h @ Whh^T + bih + bhh ; gates i,f,g,o ; c,h update.
// Block: 64 rows x 32 jj-columns (x4 gates = 128 z-cols). 256 threads,
// thread tile = 8 rows x 4 gates at one jj.
template<int KX, bool STRIDED>
__global__ __launch_bounds__(256)
void lstm_step_kernel(const float* __restrict__ xt, int xt_row_stride, int xt_k_stride,
                      const float* __restrict__ h_in,
                      float* c_state,                       // in-place (elementwise safe)
                      const float* __restrict__ Wih,       // 512 x KX
                      const float* __restrict__ Whh,       // 512 x 128
                      const float* __restrict__ bih, const float* __restrict__ bhh,
                      float* __restrict__ h_out,
                      int n)
{
    __shared__ float As[32][68];    // [k][row], padded: 68*4B = 17*16B -> b128-aligned rows
    __shared__ float Bs[32][132];   // [k][gate*32+jj]
    const int tid = threadIdx.x;
    const int jx  = tid & 31;
    const int ry  = tid >> 5;                  // 0..7
    const int rowbase = blockIdx.y * 64;
    const int c0 = blockIdx.x * 32;            // jj base

    float acc[8][4];
    #pragma unroll
    for (int r = 0; r < 8; ++r)
        #pragma unroll
        for (int g = 0; g < 4; ++g) acc[r][g] = 0.f;

    #pragma unroll
    for (int phase = 0; phase < 2; ++phase) {
        const float* Ag = phase ? h_in : xt;
        const float* Wg = phase ? Whh : Wih;
        const int KA = phase ? Hdim : KX;
        for (int k0 = 0; k0 < KA; k0 += 32) {
            {   // A tile: 64 rows x 32 k
                const int kq = tid & 7, row = tid >> 3;
                #pragma unroll
                for (int hh = 0; hh < 2; ++hh) {
                    const int r = row + hh * 32;
                    const int grow = rowbase + r;
                    float4 v = make_float4(0.f, 0.f, 0.f, 0.f);
                    if (grow < n) {
                        if (phase == 0 && STRIDED) {
                            const float* p = Ag + (size_t)grow * xt_row_stride
                                                + (size_t)(k0 + kq * 4) * xt_k_stride;
                            v.x = p[0]; v.y = p[xt_k_stride];
                            v.z = p[2 * xt_k_stride]; v.w = p[3 * xt_k_stride];
                        } else {
                            v = *reinterpret_cast<const float4*>(
                                    Ag + (size_t)grow * KA + k0 + kq * 4);
                        }
                    }
                    As[kq*4+0][r] = v.x; As[kq*4+1][r] = v.y;
                    As[kq*4+2][r] = v.z; As[kq*4+3][r] = v.w;
                }
            }
            {   // B tile: W rows (coalesced along k) -> Bs[k][gate*32+jj]
                const int kq = tid & 7;
                const int colb = tid >> 3;  // 0..31
                #pragma unroll
                for (int cc = 0; cc < 4; ++cc) {
                    const int c = colb + cc * 32;
                    const int gate = c >> 5, jj = c & 31;
                    float4 v = *reinterpret_cast<const float4*>(
                        Wg + (size_t)(gate * Hdim + c0 + jj) * KA + k0 + kq * 4);
                    Bs[kq*4+0][c] = v.x; Bs[kq*4+1][c] = v.y;
                    Bs[kq*4+2][c] = v.z; Bs[kq*4+3][c] = v.w;
                }
            }
            __syncthreads();
            #pragma unroll
            for (int k = 0; k < 32; ++k) {
                float a[8];
                float4 a0 = *reinterpret_cast<const float4*>(&As[k][ry * 8]);
                float4 a1 = *reinterpret_cast<const float4*>(&As[k][ry * 8 + 4]);
                a[0]=a0.x; a[1]=a0.y; a[2]=a0.z; a[3]=a0.w;
                a[4]=a1.x; a[5]=a1.y; a[6]=a1.z; a[7]=a1.w;
                const float b0 = Bs[k][jx], b1 = Bs[k][32+jx];
                const float b2 = Bs[k][64+jx], b3 = Bs[k][96+jx];
                #pragma unroll
                for (int r = 0; r < 8; ++r) {
                    acc[r][0] = fmaf(a[r], b0, acc[r][0]);
                    acc[r][1] = fmaf(a[r], b1, acc[r][1]);
                    acc[r][2] = fmaf(a[r], b2, acc[r][2]);
                    acc[r][3] = fmaf(a[r], b3, acc[r][3]);
                }
            }
            __syncthreads();
        }
    }
    // epilogue: gates + state update
    const int jj = c0 + jx;
    const float bi = bih[jj]          + bhh[jj];
    const float bf = bih[Hdim + jj]   + bhh[Hdim + jj];
    const float bg = bih[2*Hdim + jj] + bhh[2*Hdim + jj];
    const float bo = bih[3*Hdim + jj] + bhh[3*Hdim + jj];
    #pragma unroll
    for (int r = 0; r < 8; ++r) {
        const int grow = rowbase + ry * 8 + r;
        if (grow < n) {
            const float zi = acc[r][0] + bi;
            const float zf = acc[r][1] + bf;
            const float zg = acc[r][2] + bg;
            const float zo = acc[r][3] + bo;
            const size_t idx = (size_t)grow * Hdim + jj;
            const float co = c_state[idx];
            const float cn = sigf(zf) * co + sigf(zi) * tanh_fast(zg);
            c_state[idx] = cn;
            h_out[idx] = sigf(zo) * tanh_fast(cn);
        }
    }
}

// ---------------- plain GEMM: C[n x 128] = A[n x 128] @ B[128 x 128] ----------------
__global__ __launch_bounds__(256)
void gemm_h_kernel(const float* __restrict__ A, const float* __restrict__ B,
                   float* __restrict__ C, int n)
{
    __shared__ float As[32][68];
    __shared__ float Bs[32][128];
    const int tid = threadIdx.x;
    const int jx = tid & 31;
    const int ry = tid >> 5;
    const int rowbase = blockIdx.x * 64;
    float acc[8][4];
    #pragma unroll
    for (int r = 0; r < 8; ++r)
        #pragma unroll
        for (int q = 0; q < 4; ++q) acc[r][q] = 0.f;

    for (int k0 = 0; k0 < 128; k0 += 32) {
        {
            const int kq = tid & 7, row = tid >> 3;
            #pragma unroll
            for (int hh = 0; hh < 2; ++hh) {
                const int r = row + hh * 32;
                const int grow = rowbase + r;
                float4 v = make_float4(0.f, 0.f, 0.f, 0.f);
                if (grow < n) v = *reinterpret_cast<const float4*>(
                                    A + (size_t)grow * 128 + k0 + kq * 4);
                As[kq*4+0][r] = v.x; As[kq*4+1][r] = v.y;
                As[kq*4+2][r] = v.z; As[kq*4+3][r] = v.w;
            }
        }
        {   // B rows k0..k0+31 are 4096 contiguous floats
            const float4* src = reinterpret_cast<const float4*>(B + (size_t)k0 * 128);
            float4* dst = reinterpret_cast<float4*>(&Bs[0][0]);
            for (int i = tid; i < 1024; i += 256) dst[i] = src[i];
        }
        __syncthreads();
        #pragma unroll
        for (int k = 0; k < 32; ++k) {
            float a[8];
            float4 a0 = *reinterpret_cast<const float4*>(&As[k][ry * 8]);
            float4 a1 = *reinterpret_cast<const float4*>(&As[k][ry * 8 + 4]);
            a[0]=a0.x; a[1]=a0.y; a[2]=a0.z; a[3]=a0.w;
            a[4]=a1.x; a[5]=a1.y; a[6]=a1.z; a[7]=a1.w;
            const float b0 = Bs[k][jx], b1 = Bs[k][jx+32];
            const float b2 = Bs[k][jx+64], b3 = Bs[k][jx+96];
            #pragma unroll
            for (int r = 0; r < 8; ++r) {
                acc[r][0] = fmaf(a[r], b0, acc[r][0]);
                acc[r][1] = fmaf(a[r], b1, acc[r][1]);
                acc[r][2] = fmaf(a[r], b2, acc[r][2]);
                acc[r][3] = fmaf(a[r], b3, acc[r][3]);
            }
        }
        __syncthreads();
    }
    #pragma unroll
    for (int r = 0; r < 8; ++r) {
        const int grow = rowbase + ry * 8 + r;
        if (grow < n) {
            #pragma unroll
            for (int q = 0; q < 4; ++q)
                C[(size_t)grow * 128 + jx + q * 32] = acc[r][q];
        }
    }
}

// ---------------- GCN helpers ----------------
__global__ __launch_bounds__(256)
void edge_deg_kernel(const int* __restrict__ dst, const float* __restrict__ w,
                     float* deg, int E) {
    int e = blockIdx.x * 256 + threadIdx.x;
    if (e < E) atomicAdd(&deg[dst[e]], w[e]);
}

__global__ __launch_bounds__(256)
void dinv_kernel(float* deg_dinv, int n) {
    int i = blockIdx.x * 256 + threadIdx.x;
    if (i < n) deg_dinv[i] = rsqrtf(deg_dinv[i] + 1.0f);  // +1 = self-loop weight
}

// agg = hlin * dinv^2 (self loop) + bias  -- full overwrite, no memset needed
__global__ __launch_bounds__(256)
void agg_init_kernel(const float* __restrict__ hlin, const float* __restrict__ dinv,
                     const float* __restrict__ bias, float* __restrict__ agg, int n) {
    int idx = blockIdx.x * 256 + threadIdx.x;
    if (idx < n * Hdim) {
        int node = idx >> 7, f = idx & 127;
        float di = dinv[node];
        agg[idx] = hlin[idx] * di * di + bias[f];
    }
}

__global__ __launch_bounds__(256)
void edge_msg_kernel(const int* __restrict__ src, const int* __restrict__ dst,
                     const float* __restrict__ w, const float* __restrict__ dinv,
                     const float* __restrict__ hlin, float* agg, int E) {
    int e = blockIdx.x * 2 + (threadIdx.x >> 7);
    int f = threadIdx.x & 127;
    if (e < E) {
        int s = src[e], d = dst[e];
        float norm = dinv[s] * w[e] * dinv[d];
        atomicAdd(&agg[(size_t)d * Hdim + f], hlin[(size_t)s * Hdim + f] * norm);
    }
}

template<bool RELU>
__global__ __launch_bounds__(256)
void layernorm_kernel(const float* __restrict__ in, const float* __restrict__ gamma,
                      const float* __restrict__ beta, float* __restrict__ out, int n) {
    const int wave = threadIdx.x >> 6;
    const int lane = threadIdx.x & 63;
    const int row = blockIdx.x * 4 + wave;
    if (row >= n) return;
    float x0 = in[(size_t)row * 128 + lane];
    float x1 = in[(size_t)row * 128 + 64 + lane];
    float s = x0 + x1;
    #pragma unroll
    for (int m = 32; m >= 1; m >>= 1) s += __shfl_xor(s, m);
    const float mu = s * (1.f / 128.f);
    const float d0 = x0 - mu, d1 = x1 - mu;
    float v = d0 * d0 + d1 * d1;
    #pragma unroll
    for (int m = 32; m >= 1; m >>= 1) v += __shfl_xor(v, m);
    const float rs = rsqrtf(v * (1.f / 128.f) + 1e-5f);
    float y0 = d0 * rs * gamma[lane] + beta[lane];
    float y1 = d1 * rs * gamma[64 + lane] + beta[64 + lane];
    if (RELU) { y0 = fmaxf(y0, 0.f); y1 = fmaxf(y1, 0.f); }
    out[(size_t)row * 128 + lane] = y0;
    out[(size_t)row * 128 + 64 + lane] = y1;
}

// ---------------- fused predictor: relu(fused@Wp1+bp1)@Wp2+bp2 ----------------
__global__ __launch_bounds__(256)
void predictor_kernel(const float* __restrict__ temporal, const float* __restrict__ gfeat,
                      const float* __restrict__ Wp1, const float* __restrict__ bp1,
                      const float* __restrict__ Wp2, const float* __restrict__ bp2,
                      float* __restrict__ out, int n) {
    __shared__ float Ws[256 * 64];  // 64 KiB: whole Wp1
    const int tid = threadIdx.x;
    {
        const float4* src = reinterpret_cast<const float4*>(Wp1);
        float4* dst = reinterpret_cast<float4*>(Ws);
        for (int i = tid; i < 4096; i += 256) dst[i] = src[i];
    }
    __syncthreads();
    const int wave = tid >> 6, lane = tid & 63;
    const float b1 = bp1[lane];
    const float w2 = Wp2[lane];
    const float b2 = bp2[0];
    for (int q = 0; q < 8; ++q) {
        const int node = blockIdx.x * 32 + wave * 8 + q;
        if (node >= n) continue;   // wave-uniform
        float fv0 = temporal[(size_t)node * 128 + lane];
        float fv1 = temporal[(size_t)node * 128 + 64 + lane];
        float fv2 = gfeat[(size_t)node * 128 + lane];
        float fv3 = gfeat[(size_t)node * 128 + 64 + lane];
        float acc = b1;
        #pragma unroll
        for (int l = 0; l < 64; ++l) {
            acc = fmaf(__shfl(fv0, l), Ws[l * 64 + lane], acc);
            acc = fmaf(__shfl(fv1, l), Ws[(64 + l) * 64 + lane], acc);
            acc = fmaf(__shfl(fv2, l), Ws[(128 + l) * 64 + lane], acc);
            acc = fmaf(__shfl(fv3, l), Ws[(192 + l) * 64 + lane], acc);
        }
        float p = fmaxf(acc, 0.f) * w2;
        #pragma unroll
        for (int m = 32; m >= 1; m >>= 1) p += __shfl_xor(p, m);
        if (lane == 0) out[node] = p + b2;
    }
}

extern "C" void kernel_launch(void* const* d_in, const int* in_sizes, int n_in,
                              void* d_out, int out_size, void* d_ws, size_t ws_size,
                              hipStream_t stream) {
    const float* x    = (const float*)d_in[0];
    const int*   ei   = (const int*)d_in[1];
    const float* ew   = (const float*)d_in[2];
    const float* Wih0 = (const float*)d_in[3];
    const float* Whh0 = (const float*)d_in[4];
    const float* bih0 = (const float*)d_in[5];
    const float* bhh0 = (const float*)d_in[6];
    const float* Wih1 = (const float*)d_in[7];
    const float* Whh1 = (const float*)d_in[8];
    const float* bih1 = (const float*)d_in[9];
    const float* bhh1 = (const float*)d_in[10];
    const float* Wg1  = (const float*)d_in[11];
    const float* bg1  = (const float*)d_in[12];
    const float* g1   = (const float*)d_in[13];
    const float* be1  = (const float*)d_in[14];
    const float* Wg2  = (const float*)d_in[15];
    const float* bg2  = (const float*)d_in[16];
    const float* g2   = (const float*)d_in[17];
    const float* be2  = (const float*)d_in[18];
    const float* Wp1  = (const float*)d_in[19];
    const float* bp1  = (const float*)d_in[20];
    const float* Wp2  = (const float*)d_in[21];
    const float* bp2  = (const float*)d_in[22];
    float* out = (float*)d_out;

    const int n = in_sizes[0] / (Fdim * Tdim);
    const int E = in_sizes[1] / 2;
    const int* esrc = ei;
    const int* edst = ei + E;

    float* ws = (float*)d_ws;
    const size_t NH = (size_t)n * Hdim;
    const size_t NF = (size_t)n * Fdim;

    // Full layout: [xs: NF*T = 4*NH][h0a][h0b][c0][h1a][h1b][c1][dinv]
    const size_t need_full = NF * Tdim + 6 * NH + (size_t)n;
    const bool use_xs = ws_size >= need_full * sizeof(float);

    float* xs  = ws;
    float* h0a = ws + (use_xs ? NF * Tdim : 0);
    float* h0b = h0a + NH;
    float* c0  = h0b + NH;
    float* h1a = c0 + NH;
    float* h1b = h1a + NH;
    float* c1  = h1b + NH;
    float* dinv = c1 + NH;
    float *G1, *G2, *G3;   // graph-phase scratch (N x H each)
    if (use_xs) { G1 = ws; G2 = ws + NH; G3 = ws + 2 * NH; }  // xs dead post-LSTM
    else        { G1 = h0a; G2 = h0b; G3 = c0; }              // L0 state dead post-LSTM

    // zero initial states
    hipMemsetAsync(h0a, 0, NH * sizeof(float), stream);
    hipMemsetAsync(c0,  0, NH * sizeof(float), stream);
    hipMemsetAsync(h1a, 0, NH * sizeof(float), stream);
    hipMemsetAsync(c1,  0, NH * sizeof(float), stream);
    hipMemsetAsync(dinv, 0, (size_t)n * sizeof(float), stream);

    if (use_xs)
        transpose_x_kernel<<<(int)((NF + 255) / 256), 256, 0, stream>>>(x, xs, (int)NF);

    // LSTM: 16 steps x 2 layers, h ping-pong, c in-place
    dim3 lgrid(4, (n + 63) / 64);
    float* h0_in = h0a; float* h0_out = h0b;
    float* h1_in = h1a; float* h1_out = h1b;
    for (int t = 0; t < Tdim; ++t) {
        if (use_xs)
            lstm_step_kernel<Fdim, false><<<lgrid, 256, 0, stream>>>(
                xs + (size_t)t * NF, 0, 0, h0_in, c0, Wih0, Whh0, bih0, bhh0, h0_out, n);
        else
            lstm_step_kernel<Fdim, true><<<lgrid, 256, 0, stream>>>(
                x + t, Fdim * Tdim, Tdim, h0_in, c0, Wih0, Whh0, bih0, bhh0, h0_out, n);
        lstm_step_kernel<Hdim, false><<<lgrid, 256, 0, stream>>>(
            h0_out, 0, 0, h1_in, c1, Wih1, Whh1, bih1, bhh1, h1_out, n);
        float* tmp;
        tmp = h0_in; h0_in = h0_out; h0_out = tmp;
        tmp = h1_in; h1_in = h1_out; h1_out = tmp;
    }
    const float* temporal = h1_in;  // last written h of layer 1

    // degrees -> dinv
    edge_deg_kernel<<<(E + 255) / 256, 256, 0, stream>>>(edst, ew, dinv, E);
    dinv_kernel<<<(n + 255) / 256, 256, 0, stream>>>(dinv, n);

    const int gblocks = (n + 63) / 64;
    const int ablocks = (n * Hdim + 255) / 256;
    // GCN layer 1: hlin1=G1; agg1=G2; ln+relu -> G3
    gemm_h_kernel<<<gblocks, 256, 0, stream>>>(temporal, Wg1, G1, n);
    agg_init_kernel<<<ablocks, 256, 0, stream>>>(G1, dinv, bg1, G2, n);
    edge_msg_kernel<<<(E + 1) / 2, 256, 0, stream>>>(esrc, edst, ew, dinv, G1, G2, E);
    layernorm_kernel<true><<<(n + 3) / 4, 256, 0, stream>>>(G2, g1, be1, G3, n);
    // GCN layer 2: hlin2=G1; agg2=G2; ln -> G3 (= graph_feat)
    gemm_h_kernel<<<gblocks, 256, 0, stream>>>(G3, Wg2, G1, n);
    agg_init_kernel<<<ablocks, 256, 0, stream>>>(G1, dinv, bg2, G2, n);
    edge_msg_kernel<<<(E + 1) / 2, 256, 0, stream>>>(esrc, edst, ew, dinv, G1, G2, E);
    layernorm_kernel<false><<<(n + 3) / 4, 256, 0, stream>>>(G2, g2, be2, G3, n);

    // predictor
    predictor_kernel<<<(n + 31) / 32, 256, 0, stream>>>(
        temporal, G3, Wp1, bp1, Wp2, bp2, out, n);
}

// Round 3
// 3230.598 us; speedup vs baseline: 2.4275x; 2.4275x over previous
//
#include <hip/hip_runtime.h>
#include <math.h>

#define Hdim 128
#define Fdim 32
#define Tdim 16

typedef short  bfrag8 __attribute__((ext_vector_type(8)));
typedef float  facc4  __attribute__((ext_vector_type(4)));
typedef unsigned short ushort_t;

__device__ __forceinline__ float sigf(float x) {
    return 1.0f / (1.0f + __expf(-x));
}
__device__ __forceinline__ float tanh_fast(float x) {
    x = fminf(fmaxf(x, -15.f), 15.f);
    float e = __expf(2.f * x);
    return (e - 1.f) / (e + 1.f);
}
__device__ __forceinline__ ushort_t f2bf(float f) {
    union { float f; unsigned u; } v; v.f = f;
    unsigned u = v.u;
    unsigned r = u + 0x7fffu + ((u >> 16) & 1u);   // RNE
    return (ushort_t)(r >> 16);
}

// ---------------- f32 -> bf16 convert (weights) ----------------
__global__ __launch_bounds__(256)
void cvt_bf16_kernel(const float* __restrict__ in, ushort_t* __restrict__ out, int nelem) {
    int i = (blockIdx.x * 256 + threadIdx.x) * 4;
    if (i < nelem) {
        float4 v = *reinterpret_cast<const float4*>(in + i);
        out[i + 0] = f2bf(v.x); out[i + 1] = f2bf(v.y);
        out[i + 2] = f2bf(v.z); out[i + 3] = f2bf(v.w);
    }
}

__global__ __launch_bounds__(256)
void bias_add_kernel(const float* __restrict__ a, const float* __restrict__ b,
                     float* __restrict__ out, int n) {
    int i = blockIdx.x * 256 + threadIdx.x;
    if (i < n) out[i] = a[i] + b[i];
}

// ---------------- x (N,F,T) f32 -> xs (T,N,F) bf16 ----------------
__global__ __launch_bounds__(256)
void transpose_x_kernel(const float* __restrict__ x, ushort_t* __restrict__ xs, int nf) {
    int tid = blockIdx.x * 256 + threadIdx.x;  // over N*F
    if (tid >= nf) return;
    const float4* src = reinterpret_cast<const float4*>(x + (size_t)tid * Tdim);
    float4 a = src[0], b = src[1], c = src[2], d = src[3];
    float v[16] = {a.x,a.y,a.z,a.w, b.x,b.y,b.z,b.w, c.x,c.y,c.z,c.w, d.x,d.y,d.z,d.w};
    #pragma unroll
    for (int t = 0; t < Tdim; ++t) xs[(size_t)t * nf + tid] = f2bf(v[t]);
}

// fallback: extract slice t of x -> xt (N,F) bf16
__global__ __launch_bounds__(256)
void xslice_kernel(const float* __restrict__ x, ushort_t* __restrict__ xt, int t, int n) {
    int idx = blockIdx.x * 256 + threadIdx.x;
    if (idx < n * Fdim) {
        int node = idx >> 5, f = idx & 31;
        xt[idx] = f2bf(x[(size_t)node * (Fdim * Tdim) + f * Tdim + t]);
    }
}

// ---------------- MFMA LSTM step ----------------
// z = [xt|h] @ [Wx|Wh]^T + bias; gates i,f,g,o; c,h update.
// Block: 128 rows x 32 jj x 4 gates. 4 waves (2 row x 2 jj), each wave
// 64 rows x 16 jj x 4 gates = acc[4][4] of 16x16 frags (frag col dim = gate).
template<int Kp>
__device__ __forceinline__ void lstm_phase(const ushort_t* __restrict__ Ap,
                                           const ushort_t* __restrict__ Wp,
                                           facc4 (&acc)[4][4],
                                           int rb, int jb, int rl, int ks, int n)
{
    #pragma unroll
    for (int k0 = 0; k0 < Kp; k0 += 32) {
        const int kk = k0 + ks * 8;
        bfrag8 bfr[4];
        #pragma unroll
        for (int g = 0; g < 4; ++g)
            bfr[g] = *reinterpret_cast<const bfrag8*>(
                Wp + (size_t)(g * Hdim + jb + rl) * Kp + kk);
        #pragma unroll
        for (int m = 0; m < 4; ++m) {
            int ar = rb + m * 16 + rl;
            ar = ar < n ? ar : n - 1;                 // clamp; stores are masked
            bfrag8 afr = *reinterpret_cast<const bfrag8*>(
                Ap + (size_t)ar * Kp + kk);
            #pragma unroll
            for (int g = 0; g < 4; ++g)
                acc[m][g] = __builtin_amdgcn_mfma_f32_16x16x32_bf16(
                    afr, bfr[g], acc[m][g], 0, 0, 0);
        }
    }
}

template<int KX, bool LAST>
__global__ __launch_bounds__(256)
void lstm_mfma_kernel(const ushort_t* __restrict__ xt, const ushort_t* __restrict__ h_in,
                      float* __restrict__ c_state,
                      const ushort_t* __restrict__ Wx, const ushort_t* __restrict__ Wh,
                      const float* __restrict__ bias,
                      ushort_t* __restrict__ h_out, float* __restrict__ h_f32, int n)
{
    const int tid  = threadIdx.x;
    const int lane = tid & 63;
    const int w    = tid >> 6;
    const int wr   = w >> 1, wc = w & 1;
    const int rb   = blockIdx.x * 128 + wr * 64;
    const int jb   = blockIdx.y * 32 + wc * 16;
    const int rl   = lane & 15;          // row-in-frag (A) / col-in-frag (B,C)
    const int ks   = lane >> 4;          // k-slot

    facc4 acc[4][4] = {};                // [row-frag m][gate]

    lstm_phase<KX>(xt, Wx, acc, rb, jb, rl, ks, n);
    lstm_phase<Hdim>(h_in, Wh, acc, rb, jb, rl, ks, n);

    // epilogue: C layout col=lane&15, row=(lane>>4)*4+j  [m89-verified]
    const int jj = jb + rl;
    const float bi = bias[jj];
    const float bf_ = bias[Hdim + jj];
    const float bg = bias[2 * Hdim + jj];
    const float bo = bias[3 * Hdim + jj];
    #pragma unroll
    for (int m = 0; m < 4; ++m) {
        #pragma unroll
        for (int j = 0; j < 4; ++j) {
            const int r = rb + m * 16 + ks * 4 + j;
            if (r < n) {
                const size_t idx = (size_t)r * Hdim + jj;
                const float zi = acc[m][0][j] + bi;
                const float zf = acc[m][1][j] + bf_;
                const float zg = acc[m][2][j] + bg;
                const float zo = acc[m][3][j] + bo;
                const float co = c_state[idx];
                const float cn = sigf(zf) * co + sigf(zi) * tanh_fast(zg);
                c_state[idx] = cn;
                const float h = sigf(zo) * tanh_fast(cn);
                h_out[idx] = f2bf(h);
                if (LAST) h_f32[idx] = h;
            }
        }
    }
}

// ---------------- plain GEMM: C[n x 128] = A[n x 128] @ B[128 x 128] ----------------
__global__ __launch_bounds__(256)
void gemm_h_kernel(const float* __restrict__ A, const float* __restrict__ B,
                   float* __restrict__ C, int n)
{
    __shared__ float As[32][68];
    __shared__ float Bs[32][128];
    const int tid = threadIdx.x;
    const int jx = tid & 31;
    const int ry = tid >> 5;
    const int rowbase = blockIdx.x * 64;
    float acc[8][4];
    #pragma unroll
    for (int r = 0; r < 8; ++r)
        #pragma unroll
        for (int q = 0; q < 4; ++q) acc[r][q] = 0.f;

    for (int k0 = 0; k0 < 128; k0 += 32) {
        {
            const int kq = tid & 7, row = tid >> 3;
            #pragma unroll
            for (int hh = 0; hh < 2; ++hh) {
                const int r = row + hh * 32;
                const int grow = rowbase + r;
                float4 v = make_float4(0.f, 0.f, 0.f, 0.f);
                if (grow < n) v = *reinterpret_cast<const float4*>(
                                    A + (size_t)grow * 128 + k0 + kq * 4);
                As[kq*4+0][r] = v.x; As[kq*4+1][r] = v.y;
                As[kq*4+2][r] = v.z; As[kq*4+3][r] = v.w;
            }
        }
        {
            const float4* src = reinterpret_cast<const float4*>(B + (size_t)k0 * 128);
            float4* dst = reinterpret_cast<float4*>(&Bs[0][0]);
            for (int i = tid; i < 1024; i += 256) dst[i] = src[i];
        }
        __syncthreads();
        #pragma unroll
        for (int k = 0; k < 32; ++k) {
            float a[8];
            float4 a0 = *reinterpret_cast<const float4*>(&As[k][ry * 8]);
            float4 a1 = *reinterpret_cast<const float4*>(&As[k][ry * 8 + 4]);
            a[0]=a0.x; a[1]=a0.y; a[2]=a0.z; a[3]=a0.w;
            a[4]=a1.x; a[5]=a1.y; a[6]=a1.z; a[7]=a1.w;
            const float b0 = Bs[k][jx], b1 = Bs[k][jx+32];
            const float b2 = Bs[k][jx+64], b3 = Bs[k][jx+96];
            #pragma unroll
            for (int r = 0; r < 8; ++r) {
                acc[r][0] = fmaf(a[r], b0, acc[r][0]);
                acc[r][1] = fmaf(a[r], b1, acc[r][1]);
                acc[r][2] = fmaf(a[r], b2, acc[r][2]);
                acc[r][3] = fmaf(a[r], b3, acc[r][3]);
            }
        }
        __syncthreads();
    }
    #pragma unroll
    for (int r = 0; r < 8; ++r) {
        const int grow = rowbase + ry * 8 + r;
        if (grow < n) {
            #pragma unroll
            for (int q = 0; q < 4; ++q)
                C[(size_t)grow * 128 + jx + q * 32] = acc[r][q];
        }
    }
}

// ---------------- GCN helpers ----------------
__global__ __launch_bounds__(256)
void edge_deg_kernel(const int* __restrict__ dst, const float* __restrict__ w,
                     float* deg, int E) {
    int e = blockIdx.x * 256 + threadIdx.x;
    if (e < E) atomicAdd(&deg[dst[e]], w[e]);
}

__global__ __launch_bounds__(256)
void dinv_kernel(float* deg_dinv, int n) {
    int i = blockIdx.x * 256 + threadIdx.x;
    if (i < n) deg_dinv[i] = rsqrtf(deg_dinv[i] + 1.0f);  // +1 = self-loop
}

__global__ __launch_bounds__(256)
void agg_init_kernel(const float* __restrict__ hlin, const float* __restrict__ dinv,
                     const float* __restrict__ bias, float* __restrict__ agg, int n) {
    int idx = blockIdx.x * 256 + threadIdx.x;
    if (idx < n * Hdim) {
        int node = idx >> 7, f = idx & 127;
        float di = dinv[node];
        agg[idx] = hlin[idx] * di * di + bias[f];
    }
}

__global__ __launch_bounds__(256)
void edge_msg_kernel(const int* __restrict__ src, const int* __restrict__ dst,
                     const float* __restrict__ w, const float* __restrict__ dinv,
                     const float* __restrict__ hlin, float* agg, int E) {
    int e = blockIdx.x * 2 + (threadIdx.x >> 7);
    int f = threadIdx.x & 127;
    if (e < E) {
        int s = src[e], d = dst[e];
        float norm = dinv[s] * w[e] * dinv[d];
        atomicAdd(&agg[(size_t)d * Hdim + f], hlin[(size_t)s * Hdim + f] * norm);
    }
}

template<bool RELU>
__global__ __launch_bounds__(256)
void layernorm_kernel(const float* __restrict__ in, const float* __restrict__ gamma,
                      const float* __restrict__ beta, float* __restrict__ out, int n) {
    const int wave = threadIdx.x >> 6;
    const int lane = threadIdx.x & 63;
    const int row = blockIdx.x * 4 + wave;
    if (row >= n) return;
    float x0 = in[(size_t)row * 128 + lane];
    float x1 = in[(size_t)row * 128 + 64 + lane];
    float s = x0 + x1;
    #pragma unroll
    for (int m = 32; m >= 1; m >>= 1) s += __shfl_xor(s, m);
    const float mu = s * (1.f / 128.f);
    const float d0 = x0 - mu, d1 = x1 - mu;
    float v = d0 * d0 + d1 * d1;
    #pragma unroll
    for (int m = 32; m >= 1; m >>= 1) v += __shfl_xor(v, m);
    const float rs = rsqrtf(v * (1.f / 128.f) + 1e-5f);
    float y0 = d0 * rs * gamma[lane] + beta[lane];
    float y1 = d1 * rs * gamma[64 + lane] + beta[64 + lane];
    if (RELU) { y0 = fmaxf(y0, 0.f); y1 = fmaxf(y1, 0.f); }
    out[(size_t)row * 128 + lane] = y0;
    out[(size_t)row * 128 + 64 + lane] = y1;
}

// ---------------- fused predictor ----------------
__global__ __launch_bounds__(256)
void predictor_kernel(const float* __restrict__ temporal, const float* __restrict__ gfeat,
                      const float* __restrict__ Wp1, const float* __restrict__ bp1,
                      const float* __restrict__ Wp2, const float* __restrict__ bp2,
                      float* __restrict__ out, int n) {
    __shared__ float Ws[256 * 64];
    const int tid = threadIdx.x;
    {
        const float4* src = reinterpret_cast<const float4*>(Wp1);
        float4* dst = reinterpret_cast<float4*>(Ws);
        for (int i = tid; i < 4096; i += 256) dst[i] = src[i];
    }
    __syncthreads();
    const int wave = tid >> 6, lane = tid & 63;
    const float b1 = bp1[lane];
    const float w2 = Wp2[lane];
    const float b2 = bp2[0];
    for (int q = 0; q < 8; ++q) {
        const int node = blockIdx.x * 32 + wave * 8 + q;
        if (node >= n) continue;
        float fv0 = temporal[(size_t)node * 128 + lane];
        float fv1 = temporal[(size_t)node * 128 + 64 + lane];
        float fv2 = gfeat[(size_t)node * 128 + lane];
        float fv3 = gfeat[(size_t)node * 128 + 64 + lane];
        float acc = b1;
        #pragma unroll
        for (int l = 0; l < 64; ++l) {
            acc = fmaf(__shfl(fv0, l), Ws[l * 64 + lane], acc);
            acc = fmaf(__shfl(fv1, l), Ws[(64 + l) * 64 + lane], acc);
            acc = fmaf(__shfl(fv2, l), Ws[(128 + l) * 64 + lane], acc);
            acc = fmaf(__shfl(fv3, l), Ws[(192 + l) * 64 + lane], acc);
        }
        float p = fmaxf(acc, 0.f) * w2;
        #pragma unroll
        for (int m = 32; m >= 1; m >>= 1) p += __shfl_xor(p, m);
        if (lane == 0) out[node] = p + b2;
    }
}

extern "C" void kernel_launch(void* const* d_in, const int* in_sizes, int n_in,
                              void* d_out, int out_size, void* d_ws, size_t ws_size,
                              hipStream_t stream) {
    const float* x    = (const float*)d_in[0];
    const int*   ei   = (const int*)d_in[1];
    const float* ew   = (const float*)d_in[2];
    const float* Wih0 = (const float*)d_in[3];
    const float* Whh0 = (const float*)d_in[4];
    const float* bih0 = (const float*)d_in[5];
    const float* bhh0 = (const float*)d_in[6];
    const float* Wih1 = (const float*)d_in[7];
    const float* Whh1 = (const float*)d_in[8];
    const float* bih1 = (const float*)d_in[9];
    const float* bhh1 = (const float*)d_in[10];
    const float* Wg1  = (const float*)d_in[11];
    const float* bg1  = (const float*)d_in[12];
    const float* g1   = (const float*)d_in[13];
    const float* be1  = (const float*)d_in[14];
    const float* Wg2  = (const float*)d_in[15];
    const float* bg2  = (const float*)d_in[16];
    const float* g2   = (const float*)d_in[17];
    const float* be2  = (const float*)d_in[18];
    const float* Wp1  = (const float*)d_in[19];
    const float* bp1  = (const float*)d_in[20];
    const float* Wp2  = (const float*)d_in[21];
    const float* bp2  = (const float*)d_in[22];
    float* out = (float*)d_out;

    const int n = in_sizes[0] / (Fdim * Tdim);
    const int E = in_sizes[1] / 2;
    const int* esrc = ei;
    const int* edst = ei + E;

    const size_t NH = (size_t)n * Hdim;
    const size_t NF = (size_t)n * Fdim;

    // ---- workspace layout (byte bump-allocator, 256B aligned) ----
    const size_t wsz_weights = (size_t)(512 * Fdim + 3 * 512 * Hdim) * 2;
    const size_t need_rest = 4 * (NH * 2)      // h bufs bf16
                           + 2 * (NH * 4)      // c bufs f32
                           + (NH * 4)          // temporal f32
                           + (size_t)n * 4     // dinv
                           + wsz_weights + 2 * 512 * 4 + 8192;
    const bool use_xs = ws_size >= NF * Tdim * 2 + need_rest;

    char* base = (char*)d_ws;
    size_t off = 0;
    auto alloc = [&](size_t bytes) -> char* {
        off = (off + 255) & ~(size_t)255;
        char* p = base + off;
        off += bytes;
        return p;
    };
    ushort_t* xs   = (ushort_t*)alloc(use_xs ? NF * Tdim * 2 : NF * 2); // full or slice
    ushort_t* h0a  = (ushort_t*)alloc(NH * 2);
    ushort_t* h0b  = (ushort_t*)alloc(NH * 2);
    ushort_t* h1a  = (ushort_t*)alloc(NH * 2);
    ushort_t* h1b  = (ushort_t*)alloc(NH * 2);
    float*    c0   = (float*)alloc(NH * 4);
    float*    c1   = (float*)alloc(NH * 4);
    float*    temporal = (float*)alloc(NH * 4);
    float*    dinv = (float*)alloc((size_t)n * 4);
    ushort_t* Wx0b = (ushort_t*)alloc((size_t)512 * Fdim * 2);
    ushort_t* Wh0b = (ushort_t*)alloc((size_t)512 * Hdim * 2);
    ushort_t* Wx1b = (ushort_t*)alloc((size_t)512 * Hdim * 2);
    ushort_t* Wh1b = (ushort_t*)alloc((size_t)512 * Hdim * 2);
    float*    bias0 = (float*)alloc(512 * 4);
    float*    bias1 = (float*)alloc(512 * 4);
    // graph-phase scratch aliases the LSTM-dead region at the base
    // (xs/h0/h1/c0 are all dead after the LSTM; 3*NH*4 = 76.8MB fits)
    float* G1 = (float*)base;
    float* G2 = G1 + NH;
    float* G3 = G2 + NH;

    // ---- weight/bias prep ----
    {
        const int n0 = 512 * Fdim, n1 = 512 * Hdim;
        cvt_bf16_kernel<<<(n0/4 + 255)/256, 256, 0, stream>>>(Wih0, Wx0b, n0);
        cvt_bf16_kernel<<<(n1/4 + 255)/256, 256, 0, stream>>>(Whh0, Wh0b, n1);
        cvt_bf16_kernel<<<(n1/4 + 255)/256, 256, 0, stream>>>(Wih1, Wx1b, n1);
        cvt_bf16_kernel<<<(n1/4 + 255)/256, 256, 0, stream>>>(Whh1, Wh1b, n1);
        bias_add_kernel<<<2, 256, 0, stream>>>(bih0, bhh0, bias0, 512);
        bias_add_kernel<<<2, 256, 0, stream>>>(bih1, bhh1, bias1, 512);
    }

    // zero initial states (h bf16 zero == 0x0000)
    hipMemsetAsync(h0a, 0, NH * 2, stream);
    hipMemsetAsync(h1a, 0, NH * 2, stream);
    hipMemsetAsync(c0, 0, NH * 4, stream);
    hipMemsetAsync(c1, 0, NH * 4, stream);
    hipMemsetAsync(dinv, 0, (size_t)n * 4, stream);

    if (use_xs)
        transpose_x_kernel<<<(int)((NF + 255) / 256), 256, 0, stream>>>(x, xs, (int)NF);

    // ---- LSTM: 16 steps x 2 layers ----
    dim3 lgrid((n + 127) / 128, 4);
    ushort_t* h0_in = h0a; ushort_t* h0_out = h0b;
    ushort_t* h1_in = h1a; ushort_t* h1_out = h1b;
    for (int t = 0; t < Tdim; ++t) {
        const ushort_t* xt;
        if (use_xs) xt = xs + (size_t)t * NF;
        else {
            xslice_kernel<<<(int)((NF + 255) / 256), 256, 0, stream>>>(x, xs, t, n);
            xt = xs;
        }
        lstm_mfma_kernel<Fdim, false><<<lgrid, 256, 0, stream>>>(
            xt, h0_in, c0, Wx0b, Wh0b, bias0, h0_out, nullptr, n);
        if (t == Tdim - 1)
            lstm_mfma_kernel<Hdim, true><<<lgrid, 256, 0, stream>>>(
                h0_out, h1_in, c1, Wx1b, Wh1b, bias1, h1_out, temporal, n);
        else
            lstm_mfma_kernel<Hdim, false><<<lgrid, 256, 0, stream>>>(
                h0_out, h1_in, c1, Wx1b, Wh1b, bias1, h1_out, nullptr, n);
        ushort_t* tmp;
        tmp = h0_in; h0_in = h0_out; h0_out = tmp;
        tmp = h1_in; h1_in = h1_out; h1_out = tmp;
    }

    // ---- graph encoder ----
    edge_deg_kernel<<<(E + 255) / 256, 256, 0, stream>>>(edst, ew, dinv, E);
    dinv_kernel<<<(n + 255) / 256, 256, 0, stream>>>(dinv, n);

    const int gblocks = (n + 63) / 64;
    const int ablocks = (n * Hdim + 255) / 256;
    gemm_h_kernel<<<gblocks, 256, 0, stream>>>(temporal, Wg1, G1, n);
    agg_init_kernel<<<ablocks, 256, 0, stream>>>(G1, dinv, bg1, G2, n);
    edge_msg_kernel<<<(E + 1) / 2, 256, 0, stream>>>(esrc, edst, ew, dinv, G1, G2, E);
    layernorm_kernel<true><<<(n + 3) / 4, 256, 0, stream>>>(G2, g1, be1, G3, n);
    gemm_h_kernel<<<gblocks, 256, 0, stream>>>(G3, Wg2, G1, n);
    agg_init_kernel<<<ablocks, 256, 0, stream>>>(G1, dinv, bg2, G2, n);
    edge_msg_kernel<<<(E + 1) / 2, 256, 0, stream>>>(esrc, edst, ew, dinv, G1, G2, E);
    layernorm_kernel<false><<<(n + 3) / 4, 256, 0, stream>>>(G2, g2, be2, G3, n);

    // ---- predictor ----
    predictor_kernel<<<(n + 31) / 32, 256, 0, stream>>>(
        temporal, G3, Wp1, bp1, Wp2, bp2, out, n);
}

// Round 4
// 2495.808 us; speedup vs baseline: 3.1422x; 1.2944x over previous
//
#include <hip/hip_runtime.h>
#include <math.h>

#define Hdim 128
#define Fdim 32
#define Tdim 16

typedef short  bfrag8 __attribute__((ext_vector_type(8)));
typedef float  facc4  __attribute__((ext_vector_type(4)));
typedef unsigned short ushort_t;

__device__ __forceinline__ float sigf(float x) {
    return 1.0f / (1.0f + __expf(-x));
}
__device__ __forceinline__ float tanh_fast(float x) {
    x = fminf(fmaxf(x, -15.f), 15.f);
    float e = __expf(2.f * x);
    return (e - 1.f) / (e + 1.f);
}
__device__ __forceinline__ ushort_t f2bf(float f) {
    union { float f; unsigned u; } v; v.f = f;
    unsigned u = v.u;
    unsigned r = u + 0x7fffu + ((u >> 16) & 1u);   // RNE
    return (ushort_t)(r >> 16);
}

// ---------------- f32 -> bf16 convert (weights) ----------------
__global__ __launch_bounds__(256)
void cvt_bf16_kernel(const float* __restrict__ in, ushort_t* __restrict__ out, int nelem) {
    int i = (blockIdx.x * 256 + threadIdx.x) * 4;
    if (i < nelem) {
        float4 v = *reinterpret_cast<const float4*>(in + i);
        out[i + 0] = f2bf(v.x); out[i + 1] = f2bf(v.y);
        out[i + 2] = f2bf(v.z); out[i + 3] = f2bf(v.w);
    }
}

__global__ __launch_bounds__(256)
void bias_add_kernel(const float* __restrict__ a, const float* __restrict__ b,
                     float* __restrict__ out, int n) {
    int i = blockIdx.x * 256 + threadIdx.x;
    if (i < n) out[i] = a[i] + b[i];
}

// ---------------- x (N,F,T) f32 -> xs (T,N,F) bf16 ----------------
__global__ __launch_bounds__(256)
void transpose_x_kernel(const float* __restrict__ x, ushort_t* __restrict__ xs, int nf) {
    int tid = blockIdx.x * 256 + threadIdx.x;  // over N*F
    if (tid >= nf) return;
    const float4* src = reinterpret_cast<const float4*>(x + (size_t)tid * Tdim);
    float4 a = src[0], b = src[1], c = src[2], d = src[3];
    float v[16] = {a.x,a.y,a.z,a.w, b.x,b.y,b.z,b.w, c.x,c.y,c.z,c.w, d.x,d.y,d.z,d.w};
    #pragma unroll
    for (int t = 0; t < Tdim; ++t) xs[(size_t)t * nf + tid] = f2bf(v[t]);
}

// fallback: extract slice t of x -> xt (N,F) bf16
__global__ __launch_bounds__(256)
void xslice_kernel(const float* __restrict__ x, ushort_t* __restrict__ xt, int t, int n) {
    int idx = blockIdx.x * 256 + threadIdx.x;
    if (idx < n * Fdim) {
        int node = idx >> 5, f = idx & 31;
        xt[idx] = f2bf(x[(size_t)node * (Fdim * Tdim) + f * Tdim + t]);
    }
}

// ---------------- MFMA LSTM step core ----------------
// z = [xt|h] @ [Wx|Wh]^T + bias; gates i,f,g,o; c,h update.
// Block: 128 rows x 32 jj x 4 gates. 4 waves (2 row x 2 jj), each wave
// 64 rows x 16 jj x 4 gates = acc[4][4] of 16x16 frags.
template<int Kp>
__device__ __forceinline__ void lstm_phase(const ushort_t* __restrict__ Ap,
                                           const ushort_t* __restrict__ Wp,
                                           facc4 (&acc)[4][4],
                                           int rb, int jb, int rl, int ks, int n)
{
    #pragma unroll
    for (int k0 = 0; k0 < Kp; k0 += 32) {
        const int kk = k0 + ks * 8;
        bfrag8 bfr[4];
        #pragma unroll
        for (int g = 0; g < 4; ++g)
            bfr[g] = *reinterpret_cast<const bfrag8*>(
                Wp + (size_t)(g * Hdim + jb + rl) * Kp + kk);
        #pragma unroll
        for (int m = 0; m < 4; ++m) {
            int ar = rb + m * 16 + rl;
            ar = ar < n ? ar : n - 1;                 // clamp; stores are masked
            bfrag8 afr = *reinterpret_cast<const bfrag8*>(
                Ap + (size_t)ar * Kp + kk);
            #pragma unroll
            for (int g = 0; g < 4; ++g)
                acc[m][g] = __builtin_amdgcn_mfma_f32_16x16x32_bf16(
                    afr, bfr[g], acc[m][g], 0, 0, 0);
        }
    }
}

template<int KX>
__device__ __forceinline__
void lstm_step_core(const ushort_t* __restrict__ xt, const ushort_t* __restrict__ h_in,
                    float* __restrict__ c_state,
                    const ushort_t* __restrict__ Wx, const ushort_t* __restrict__ Wh,
                    const float* __restrict__ bias,
                    ushort_t* __restrict__ h_out, float* __restrict__ h_f32,
                    int n, int bx, int by)
{
    const int tid  = threadIdx.x;
    const int lane = tid & 63;
    const int w    = tid >> 6;
    const int wr   = w >> 1, wc = w & 1;
    const int rb   = bx * 128 + wr * 64;
    const int jb   = by * 32 + wc * 16;
    const int rl   = lane & 15;          // row-in-frag (A) / col-in-frag (B,C)
    const int ks   = lane >> 4;          // k-slot

    facc4 acc[4][4] = {};                // [row-frag m][gate]

    lstm_phase<KX>(xt, Wx, acc, rb, jb, rl, ks, n);
    lstm_phase<Hdim>(h_in, Wh, acc, rb, jb, rl, ks, n);

    // epilogue: C layout col=lane&15, row=(lane>>4)*4+j  [m89-verified]
    const int jj = jb + rl;
    const float bi = bias[jj];
    const float bf_ = bias[Hdim + jj];
    const float bg = bias[2 * Hdim + jj];
    const float bo = bias[3 * Hdim + jj];
    #pragma unroll
    for (int m = 0; m < 4; ++m) {
        #pragma unroll
        for (int j = 0; j < 4; ++j) {
            const int r = rb + m * 16 + ks * 4 + j;
            if (r < n) {
                const size_t idx = (size_t)r * Hdim + jj;
                const float zi = acc[m][0][j] + bi;
                const float zf = acc[m][1][j] + bf_;
                const float zg = acc[m][2][j] + bg;
                const float zo = acc[m][3][j] + bo;
                const float co = c_state[idx];
                const float cn = sigf(zf) * co + sigf(zi) * tanh_fast(zg);
                c_state[idx] = cn;
                const float h = sigf(zo) * tanh_fast(cn);
                h_out[idx] = f2bf(h);
                if (h_f32 != nullptr) h_f32[idx] = h;
            }
        }
    }
}

// Paired launch: z==0 -> layer0 step t (t<Tdim); z==1 -> layer1 step t-1 (t>=1).
// L1's input sequence element = h0 output of step t-1 = the h0_in buffer.
__global__ __launch_bounds__(256)
void lstm_pair_kernel(const ushort_t* __restrict__ xt,
                      const ushort_t* __restrict__ h0_in, ushort_t* __restrict__ h0_out,
                      float* __restrict__ c0,
                      const ushort_t* __restrict__ Wx0, const ushort_t* __restrict__ Wh0,
                      const float* __restrict__ b0,
                      const ushort_t* __restrict__ h1_in, ushort_t* __restrict__ h1_out,
                      float* __restrict__ c1,
                      const ushort_t* __restrict__ Wx1, const ushort_t* __restrict__ Wh1,
                      const float* __restrict__ b1,
                      float* __restrict__ temporal_or_null, int t, int n)
{
    if (blockIdx.z == 0) {
        if (t >= Tdim) return;
        lstm_step_core<Fdim>(xt, h0_in, c0, Wx0, Wh0, b0, h0_out, nullptr,
                             n, blockIdx.x, blockIdx.y);
    } else {
        if (t == 0) return;
        lstm_step_core<Hdim>(h0_in, h1_in, c1, Wx1, Wh1, b1, h1_out, temporal_or_null,
                             n, blockIdx.x, blockIdx.y);
    }
}

// ---------------- plain GEMM: C[n x 128] = A[n x 128] @ B[128 x 128] ----------------
__global__ __launch_bounds__(256)
void gemm_h_kernel(const float* __restrict__ A, const float* __restrict__ B,
                   float* __restrict__ C, int n)
{
    __shared__ float As[32][68];
    __shared__ float Bs[32][128];
    const int tid = threadIdx.x;
    const int jx = tid & 31;
    const int ry = tid >> 5;
    const int rowbase = blockIdx.x * 64;
    float acc[8][4];
    #pragma unroll
    for (int r = 0; r < 8; ++r)
        #pragma unroll
        for (int q = 0; q < 4; ++q) acc[r][q] = 0.f;

    for (int k0 = 0; k0 < 128; k0 += 32) {
        {
            const int kq = tid & 7, row = tid >> 3;
            #pragma unroll
            for (int hh = 0; hh < 2; ++hh) {
                const int r = row + hh * 32;
                const int grow = rowbase + r;
                float4 v = make_float4(0.f, 0.f, 0.f, 0.f);
                if (grow < n) v = *reinterpret_cast<const float4*>(
                                    A + (size_t)grow * 128 + k0 + kq * 4);
                As[kq*4+0][r] = v.x; As[kq*4+1][r] = v.y;
                As[kq*4+2][r] = v.z; As[kq*4+3][r] = v.w;
            }
        }
        {
            const float4* src = reinterpret_cast<const float4*>(B + (size_t)k0 * 128);
            float4* dst = reinterpret_cast<float4*>(&Bs[0][0]);
            for (int i = tid; i < 1024; i += 256) dst[i] = src[i];
        }
        __syncthreads();
        #pragma unroll
        for (int k = 0; k < 32; ++k) {
            float a[8];
            float4 a0 = *reinterpret_cast<const float4*>(&As[k][ry * 8]);
            float4 a1 = *reinterpret_cast<const float4*>(&As[k][ry * 8 + 4]);
            a[0]=a0.x; a[1]=a0.y; a[2]=a0.z; a[3]=a0.w;
            a[4]=a1.x; a[5]=a1.y; a[6]=a1.z; a[7]=a1.w;
            const float b0 = Bs[k][jx], b1 = Bs[k][jx+32];
            const float b2 = Bs[k][jx+64], b3 = Bs[k][jx+96];
            #pragma unroll
            for (int r = 0; r < 8; ++r) {
                acc[r][0] = fmaf(a[r], b0, acc[r][0]);
                acc[r][1] = fmaf(a[r], b1, acc[r][1]);
                acc[r][2] = fmaf(a[r], b2, acc[r][2]);
                acc[r][3] = fmaf(a[r], b3, acc[r][3]);
            }
        }
        __syncthreads();
    }
    #pragma unroll
    for (int r = 0; r < 8; ++r) {
        const int grow = rowbase + ry * 8 + r;
        if (grow < n) {
            #pragma unroll
            for (int q = 0; q < 4; ++q)
                C[(size_t)grow * 128 + jx + q * 32] = acc[r][q];
        }
    }
}

// ---------------- CSR build ----------------
// deg (float, weighted) and counts (int) histograms over dst
__global__ __launch_bounds__(256)
void deg_hist_kernel(const int* __restrict__ dst, const float* __restrict__ w,
                     float* deg, int* counts, int E) {
    int e = blockIdx.x * 256 + threadIdx.x;
    if (e < E) {
        int d = dst[e];
        atomicAdd(&deg[d], w[e]);
        atomicAdd(&counts[d], 1);
    }
}

__global__ __launch_bounds__(256)
void dinv_kernel(float* deg_dinv, int n) {
    int i = blockIdx.x * 256 + threadIdx.x;
    if (i < n) deg_dinv[i] = rsqrtf(deg_dinv[i] + 1.0f);  // +1 = self-loop
}

// inclusive scan per 256-block
__global__ __launch_bounds__(256)
void scan1_kernel(const int* __restrict__ counts, int* __restrict__ Sloc,
                  int* __restrict__ bsum, int n) {
    __shared__ int tmp[256];
    const int i = blockIdx.x * 256 + threadIdx.x;
    tmp[threadIdx.x] = (i < n) ? counts[i] : 0;
    __syncthreads();
    #pragma unroll
    for (int off = 1; off < 256; off <<= 1) {
        int t = (threadIdx.x >= off) ? tmp[threadIdx.x - off] : 0;
        __syncthreads();
        tmp[threadIdx.x] += t;
        __syncthreads();
    }
    if (i < n) Sloc[i] = tmp[threadIdx.x];
    if (threadIdx.x == 255) bsum[blockIdx.x] = tmp[255];
}

// inclusive scan of block sums (nb <= 256)
__global__ __launch_bounds__(256)
void scan2_kernel(int* __restrict__ bsum, int nb) {
    __shared__ int tmp[256];
    tmp[threadIdx.x] = (threadIdx.x < nb) ? bsum[threadIdx.x] : 0;
    __syncthreads();
    #pragma unroll
    for (int off = 1; off < 256; off <<= 1) {
        int t = (threadIdx.x >= off) ? tmp[threadIdx.x - off] : 0;
        __syncthreads();
        tmp[threadIdx.x] += t;
        __syncthreads();
    }
    if (threadIdx.x < nb) bsum[threadIdx.x] = tmp[threadIdx.x];
}

__global__ __launch_bounds__(256)
void scan3_kernel(const int* __restrict__ Sloc, const int* __restrict__ bsum,
                  const int* __restrict__ counts,
                  int* __restrict__ rowstart, int* __restrict__ running, int n) {
    const int i = blockIdx.x * 256 + threadIdx.x;
    if (i >= n) return;
    const int S = Sloc[i] + (blockIdx.x > 0 ? bsum[blockIdx.x - 1] : 0);
    const int rs = S - counts[i];
    rowstart[i] = rs;
    running[i]  = rs;
}

// scatter edges into CSR slots; precompute normalized weight
__global__ __launch_bounds__(256)
void scatter_kernel(const int* __restrict__ src, const int* __restrict__ dst,
                    const float* __restrict__ w, const float* __restrict__ dinv,
                    int* __restrict__ running,
                    int* __restrict__ s_srt, float* __restrict__ w_srt, int E) {
    int e = blockIdx.x * 256 + threadIdx.x;
    if (e >= E) return;
    const int s = src[e], d = dst[e];
    const int pos = atomicAdd(&running[d], 1);
    s_srt[pos] = s;
    w_srt[pos] = dinv[s] * w[e] * dinv[d];
}

// ---------------- fused gather + bias + self-loop + LayerNorm (+ReLU) ----------------
// one wave per dst node; H=128 -> 2 floats per lane
template<bool RELU>
__global__ __launch_bounds__(256)
void gather_ln_kernel(const float* __restrict__ hlin,
                      const int* __restrict__ rowstart, const int* __restrict__ counts,
                      const int* __restrict__ s_srt, const float* __restrict__ w_srt,
                      const float* __restrict__ dinv, const float* __restrict__ bias,
                      const float* __restrict__ gamma, const float* __restrict__ beta,
                      float* __restrict__ out, int n)
{
    const int wave = threadIdx.x >> 6;
    const int lane = threadIdx.x & 63;
    const int node = blockIdx.x * 4 + wave;
    if (node >= n) return;

    const float di = dinv[node];
    float a0 = hlin[(size_t)node * Hdim + lane]      * di * di + bias[lane];
    float a1 = hlin[(size_t)node * Hdim + 64 + lane] * di * di + bias[64 + lane];

    const int rs  = rowstart[node];
    const int cnt = counts[node];
    int j = rs;
    const int jend = rs + cnt;
    for (; j + 1 < jend; j += 2) {
        const int   sA = s_srt[j],     sB = s_srt[j + 1];
        const float wA = w_srt[j],     wB = w_srt[j + 1];
        const float* rA = hlin + (size_t)sA * Hdim;
        const float* rB = hlin + (size_t)sB * Hdim;
        a0 += rA[lane] * wA;      a1 += rA[64 + lane] * wA;
        a0 += rB[lane] * wB;      a1 += rB[64 + lane] * wB;
    }
    if (j < jend) {
        const int   sA = s_srt[j];
        const float wA = w_srt[j];
        const float* rA = hlin + (size_t)sA * Hdim;
        a0 += rA[lane] * wA;      a1 += rA[64 + lane] * wA;
    }

    // LayerNorm over 128
    float s = a0 + a1;
    #pragma unroll
    for (int m = 32; m >= 1; m >>= 1) s += __shfl_xor(s, m);
    const float mu = s * (1.f / 128.f);
    const float d0 = a0 - mu, d1 = a1 - mu;
    float v = d0 * d0 + d1 * d1;
    #pragma unroll
    for (int m = 32; m >= 1; m >>= 1) v += __shfl_xor(v, m);
    const float rstd = rsqrtf(v * (1.f / 128.f) + 1e-5f);
    float y0 = d0 * rstd * gamma[lane]      + beta[lane];
    float y1 = d1 * rstd * gamma[64 + lane] + beta[64 + lane];
    if (RELU) { y0 = fmaxf(y0, 0.f); y1 = fmaxf(y1, 0.f); }
    out[(size_t)node * Hdim + lane]      = y0;
    out[(size_t)node * Hdim + 64 + lane] = y1;
}

// ---------------- fused predictor ----------------
__global__ __launch_bounds__(256)
void predictor_kernel(const float* __restrict__ temporal, const float* __restrict__ gfeat,
                      const float* __restrict__ Wp1, const float* __restrict__ bp1,
                      const float* __restrict__ Wp2, const float* __restrict__ bp2,
                      float* __restrict__ out, int n) {
    __shared__ float Ws[256 * 64];
    const int tid = threadIdx.x;
    {
        const float4* src = reinterpret_cast<const float4*>(Wp1);
        float4* dst = reinterpret_cast<float4*>(Ws);
        for (int i = tid; i < 4096; i += 256) dst[i] = src[i];
    }
    __syncthreads();
    const int wave = tid >> 6, lane = tid & 63;
    const float b1 = bp1[lane];
    const float w2 = Wp2[lane];
    const float b2 = bp2[0];
    for (int q = 0; q < 8; ++q) {
        const int node = blockIdx.x * 32 + wave * 8 + q;
        if (node >= n) continue;
        float fv0 = temporal[(size_t)node * 128 + lane];
        float fv1 = temporal[(size_t)node * 128 + 64 + lane];
        float fv2 = gfeat[(size_t)node * 128 + lane];
        float fv3 = gfeat[(size_t)node * 128 + 64 + lane];
        float acc = b1;
        #pragma unroll
        for (int l = 0; l < 64; ++l) {
            acc = fmaf(__shfl(fv0, l), Ws[l * 64 + lane], acc);
            acc = fmaf(__shfl(fv1, l), Ws[(64 + l) * 64 + lane], acc);
            acc = fmaf(__shfl(fv2, l), Ws[(128 + l) * 64 + lane], acc);
            acc = fmaf(__shfl(fv3, l), Ws[(192 + l) * 64 + lane], acc);
        }
        float p = fmaxf(acc, 0.f) * w2;
        #pragma unroll
        for (int m = 32; m >= 1; m >>= 1) p += __shfl_xor(p, m);
        if (lane == 0) out[node] = p + b2;
    }
}

extern "C" void kernel_launch(void* const* d_in, const int* in_sizes, int n_in,
                              void* d_out, int out_size, void* d_ws, size_t ws_size,
                              hipStream_t stream) {
    const float* x    = (const float*)d_in[0];
    const int*   ei   = (const int*)d_in[1];
    const float* ew   = (const float*)d_in[2];
    const float* Wih0 = (const float*)d_in[3];
    const float* Whh0 = (const float*)d_in[4];
    const float* bih0 = (const float*)d_in[5];
    const float* bhh0 = (const float*)d_in[6];
    const float* Wih1 = (const float*)d_in[7];
    const float* Whh1 = (const float*)d_in[8];
    const float* bih1 = (const float*)d_in[9];
    const float* bhh1 = (const float*)d_in[10];
    const float* Wg1  = (const float*)d_in[11];
    const float* bg1  = (const float*)d_in[12];
    const float* g1   = (const float*)d_in[13];
    const float* be1  = (const float*)d_in[14];
    const float* Wg2  = (const float*)d_in[15];
    const float* bg2  = (const float*)d_in[16];
    const float* g2   = (const float*)d_in[17];
    const float* be2  = (const float*)d_in[18];
    const float* Wp1  = (const float*)d_in[19];
    const float* bp1  = (const float*)d_in[20];
    const float* Wp2  = (const float*)d_in[21];
    const float* bp2  = (const float*)d_in[22];
    float* out = (float*)d_out;

    const int n = in_sizes[0] / (Fdim * Tdim);
    const int E = in_sizes[1] / 2;
    const int* esrc = ei;
    const int* edst = ei + E;

    const size_t NH = (size_t)n * Hdim;
    const size_t NF = (size_t)n * Fdim;

    // ---- workspace layout (byte bump-allocator, 256B aligned) ----
    const size_t wsz_weights = (size_t)(512 * Fdim + 3 * 512 * Hdim) * 2;
    const size_t csr_bytes = (size_t)n * 16 + (size_t)E * 8 + 2048;
    const size_t need_rest = 4 * (NH * 2)      // h bufs bf16
                           + 2 * (NH * 4)      // c bufs f32
                           + (NH * 4)          // temporal f32
                           + (size_t)n * 4     // dinv
                           + wsz_weights + 2 * 512 * 4 + csr_bytes + 16384;
    const bool use_xs = ws_size >= NF * Tdim * 2 + need_rest;

    char* base = (char*)d_ws;
    size_t off = 0;
    auto alloc = [&](size_t bytes) -> char* {
        off = (off + 255) & ~(size_t)255;
        char* p = base + off;
        off += bytes;
        return p;
    };
    ushort_t* xs   = (ushort_t*)alloc(use_xs ? NF * Tdim * 2 : NF * 2);
    ushort_t* h0a  = (ushort_t*)alloc(NH * 2);
    ushort_t* h0b  = (ushort_t*)alloc(NH * 2);
    ushort_t* h1a  = (ushort_t*)alloc(NH * 2);
    ushort_t* h1b  = (ushort_t*)alloc(NH * 2);
    float*    c0   = (float*)alloc(NH * 4);
    float*    c1   = (float*)alloc(NH * 4);
    float*    temporal = (float*)alloc(NH * 4);
    float*    dinv = (float*)alloc((size_t)n * 4);
    ushort_t* Wx0b = (ushort_t*)alloc((size_t)512 * Fdim * 2);
    ushort_t* Wh0b = (ushort_t*)alloc((size_t)512 * Hdim * 2);
    ushort_t* Wx1b = (ushort_t*)alloc((size_t)512 * Hdim * 2);
    ushort_t* Wh1b = (ushort_t*)alloc((size_t)512 * Hdim * 2);
    float*    bias0 = (float*)alloc(512 * 4);
    float*    bias1 = (float*)alloc(512 * 4);
    // CSR arrays
    int*   counts   = (int*)alloc((size_t)n * 4);
    int*   Sloc     = (int*)alloc((size_t)n * 4);
    int*   bsum     = (int*)alloc(1024);
    int*   rowstart = (int*)alloc((size_t)n * 4);
    int*   running  = (int*)alloc((size_t)n * 4);
    int*   s_srt    = (int*)alloc((size_t)E * 4);
    float* w_srt    = (float*)alloc((size_t)E * 4);
    // graph-phase scratch aliases the LSTM-dead region at the base
    // (xs + h0a + h0b dead post-LSTM; 3*NH*4 fits in their footprint in both modes)
    float* G1 = (float*)base;
    float* G2 = G1 + NH;
    float* G3 = G2 + NH;

    // ---- weight/bias prep ----
    {
        const int n0 = 512 * Fdim, n1 = 512 * Hdim;
        cvt_bf16_kernel<<<(n0/4 + 255)/256, 256, 0, stream>>>(Wih0, Wx0b, n0);
        cvt_bf16_kernel<<<(n1/4 + 255)/256, 256, 0, stream>>>(Whh0, Wh0b, n1);
        cvt_bf16_kernel<<<(n1/4 + 255)/256, 256, 0, stream>>>(Wih1, Wx1b, n1);
        cvt_bf16_kernel<<<(n1/4 + 255)/256, 256, 0, stream>>>(Whh1, Wh1b, n1);
        bias_add_kernel<<<2, 256, 0, stream>>>(bih0, bhh0, bias0, 512);
        bias_add_kernel<<<2, 256, 0, stream>>>(bih1, bhh1, bias1, 512);
    }

    // zero initial state + histogram buffers
    hipMemsetAsync(h0a, 0, NH * 2, stream);
    hipMemsetAsync(h1a, 0, NH * 2, stream);
    hipMemsetAsync(c0, 0, NH * 4, stream);
    hipMemsetAsync(c1, 0, NH * 4, stream);
    hipMemsetAsync(dinv, 0, (size_t)n * 4, stream);
    hipMemsetAsync(counts, 0, (size_t)n * 4, stream);

    // ---- CSR build (graph shared by both GCN layers) ----
    {
        const int eb = (E + 255) / 256;
        const int nb = (n + 255) / 256;
        deg_hist_kernel<<<eb, 256, 0, stream>>>(edst, ew, dinv, counts, E);
        dinv_kernel<<<nb, 256, 0, stream>>>(dinv, n);
        scan1_kernel<<<nb, 256, 0, stream>>>(counts, Sloc, bsum, n);
        scan2_kernel<<<1, 256, 0, stream>>>(bsum, nb);
        scan3_kernel<<<nb, 256, 0, stream>>>(Sloc, bsum, counts, rowstart, running, n);
        scatter_kernel<<<eb, 256, 0, stream>>>(esrc, edst, ew, dinv, running,
                                               s_srt, w_srt, E);
    }

    if (use_xs)
        transpose_x_kernel<<<(int)((NF + 255) / 256), 256, 0, stream>>>(x, xs, (int)NF);

    // ---- LSTM: 17 paired launches (L0 step t || L1 step t-1) ----
    // h0 buffers B[]: L0 step t reads B[t&1], writes B[(t+1)&1].
    // h1 buffers H[]: L1 step s reads H[s&1], writes H[(s+1)&1]; s = t-1.
    ushort_t* B[2] = { h0a, h0b };
    ushort_t* H[2] = { h1a, h1b };
    dim3 lgrid((n + 127) / 128, 4, 2);
    for (int t = 0; t <= Tdim; ++t) {
        const ushort_t* xt = xs;
        if (t < Tdim) {
            if (use_xs) xt = xs + (size_t)t * NF;
            else {
                xslice_kernel<<<(int)((NF + 255) / 256), 256, 0, stream>>>(x, xs, t, n);
                xt = xs;
            }
        }
        float* tf32 = (t == Tdim) ? temporal : nullptr;
        lstm_pair_kernel<<<lgrid, 256, 0, stream>>>(
            xt, B[t & 1], B[(t + 1) & 1], c0, Wx0b, Wh0b, bias0,
            H[(t + 1) & 1], H[t & 1], c1, Wx1b, Wh1b, bias1,
            tf32, t, n);
    }

    // ---- graph encoder: gemm -> fused gather+LN(+ReLU) ----
    const int gblocks  = (n + 63) / 64;
    const int nwblocks = (n + 3) / 4;
    gemm_h_kernel<<<gblocks, 256, 0, stream>>>(temporal, Wg1, G1, n);
    gather_ln_kernel<true><<<nwblocks, 256, 0, stream>>>(
        G1, rowstart, counts, s_srt, w_srt, dinv, bg1, g1, be1, G3, n);
    gemm_h_kernel<<<gblocks, 256, 0, stream>>>(G3, Wg2, G1, n);
    gather_ln_kernel<false><<<nwblocks, 256, 0, stream>>>(
        G1, rowstart, counts, s_srt, w_srt, dinv, bg2, g2, be2, G2, n);

    // ---- predictor ----
    predictor_kernel<<<(n + 31) / 32, 256, 0, stream>>>(
        temporal, G2, Wp1, bp1, Wp2, bp2, out, n);
}

// Round 6
// 1790.797 us; speedup vs baseline: 4.3793x; 1.3937x over previous
//
#include <hip/hip_runtime.h>
#include <math.h>

#define Hdim 128
#define Fdim 32
#define Tdim 16

typedef short  bfrag8 __attribute__((ext_vector_type(8)));
typedef float  facc4  __attribute__((ext_vector_type(4)));
typedef unsigned short ushort_t;

__device__ __forceinline__ float sigf(float x) {
    return 1.0f / (1.0f + __expf(-x));
}
__device__ __forceinline__ float tanh_fast(float x) {
    x = fminf(fmaxf(x, -15.f), 15.f);
    float e = __expf(2.f * x);
    return (e - 1.f) / (e + 1.f);
}
__device__ __forceinline__ ushort_t f2bf(float f) {
    union { float f; unsigned u; } v; v.f = f;
    unsigned u = v.u;
    unsigned r = u + 0x7fffu + ((u >> 16) & 1u);   // RNE
    return (ushort_t)(r >> 16);
}

// ---------------- f32 -> bf16 convert (weights) ----------------
__global__ __launch_bounds__(256)
void cvt_bf16_kernel(const float* __restrict__ in, ushort_t* __restrict__ out, int nelem) {
    int i = (blockIdx.x * 256 + threadIdx.x) * 4;
    if (i < nelem) {
        float4 v = *reinterpret_cast<const float4*>(in + i);
        out[i + 0] = f2bf(v.x); out[i + 1] = f2bf(v.y);
        out[i + 2] = f2bf(v.z); out[i + 3] = f2bf(v.w);
    }
}

__global__ __launch_bounds__(256)
void bias_add_kernel(const float* __restrict__ a, const float* __restrict__ b,
                     float* __restrict__ out, int n) {
    int i = blockIdx.x * 256 + threadIdx.x;
    if (i < n) out[i] = a[i] + b[i];
}

// ---------------- x (N,F,T) f32 -> xs (T,N,F) bf16 ----------------
__global__ __launch_bounds__(256)
void transpose_x_kernel(const float* __restrict__ x, ushort_t* __restrict__ xs, int nf) {
    int tid = blockIdx.x * 256 + threadIdx.x;  // over N*F
    if (tid >= nf) return;
    const float4* src = reinterpret_cast<const float4*>(x + (size_t)tid * Tdim);
    float4 a = src[0], b = src[1], c = src[2], d = src[3];
    float v[16] = {a.x,a.y,a.z,a.w, b.x,b.y,b.z,b.w, c.x,c.y,c.z,c.w, d.x,d.y,d.z,d.w};
    #pragma unroll
    for (int t = 0; t < Tdim; ++t) xs[(size_t)t * nf + tid] = f2bf(v[t]);
}

// fallback: extract slice t of x -> xt (N,F) bf16
__global__ __launch_bounds__(256)
void xslice_kernel(const float* __restrict__ x, ushort_t* __restrict__ xt, int t, int n) {
    int idx = blockIdx.x * 256 + threadIdx.x;
    if (idx < n * Fdim) {
        int node = idx >> 5, f = idx & 31;
        xt[idx] = f2bf(x[(size_t)node * (Fdim * Tdim) + f * Tdim + t]);
    }
}

// ---------------- MFMA LSTM step (LDS-staged fragments) ----------------
// Block: 128 rows x 32 jj x 4 gates. 4 waves (2 row x 2 jj).
// Per 32-k step: stage A[128][32] and B[128][32] bf16 tiles in LDS
// (coalesced 16B loads + ds_write_b128), fragments via ds_read_b128.
// Linear [row][32] layout: b128 reads spread evenly over 8 bank-spans.
template<int Kp>
__device__ __forceinline__ void lstm_phase_lds(
    const ushort_t* __restrict__ Ap, const ushort_t* __restrict__ Wp,
    ushort_t* __restrict__ As, ushort_t* __restrict__ Bs,
    facc4 (&acc)[4][4],
    int rb_blk, int jb_blk, int wr, int wc, int rl, int ks, int tid, int n)
{
    #pragma unroll
    for (int k0 = 0; k0 < Kp; k0 += 32) {
        __syncthreads();   // previous iter's reads done before overwrite
        #pragma unroll
        for (int s = 0; s < 2; ++s) {
            const int slot = tid + 256 * s;          // 512 slots of 16B
            const int arow = slot >> 2;
            const int c8   = (slot & 3) * 8;         // ushort offset in row
            int grow = rb_blk + arow; grow = grow < n ? grow : n - 1;
            bfrag8 av = *reinterpret_cast<const bfrag8*>(
                Ap + (size_t)grow * Kp + k0 + c8);
            const int g = arow >> 5, j = arow & 31;  // B tile row -> z-row
            bfrag8 bv = *reinterpret_cast<const bfrag8*>(
                Wp + (size_t)(g * Hdim + jb_blk + j) * Kp + k0 + c8);
            *reinterpret_cast<bfrag8*>(As + slot * 8) = av;
            *reinterpret_cast<bfrag8*>(Bs + slot * 8) = bv;
        }
        __syncthreads();
        bfrag8 bfr[4];
        #pragma unroll
        for (int g = 0; g < 4; ++g)
            bfr[g] = *reinterpret_cast<const bfrag8*>(
                Bs + ((g * 32 + wc * 16 + rl) * 32 + ks * 8));
        #pragma unroll
        for (int m = 0; m < 4; ++m) {
            bfrag8 afr = *reinterpret_cast<const bfrag8*>(
                As + ((wr * 64 + m * 16 + rl) * 32 + ks * 8));
            #pragma unroll
            for (int g = 0; g < 4; ++g)
                acc[m][g] = __builtin_amdgcn_mfma_f32_16x16x32_bf16(
                    afr, bfr[g], acc[m][g], 0, 0, 0);
        }
    }
}

template<int KX>
__device__ __forceinline__
void lstm_step_core(const ushort_t* __restrict__ xt, const ushort_t* __restrict__ h_in,
                    float* __restrict__ c_state,
                    const ushort_t* __restrict__ Wx, const ushort_t* __restrict__ Wh,
                    const float* __restrict__ bias,
                    ushort_t* __restrict__ h_out, float* __restrict__ h_f32,
                    ushort_t* __restrict__ As, ushort_t* __restrict__ Bs,
                    int n, int bx, int by)
{
    const int tid  = threadIdx.x;
    const int lane = tid & 63;
    const int w    = tid >> 6;
    const int wr   = w >> 1, wc = w & 1;
    const int rb_blk = bx * 128;
    const int jb_blk = by * 32;
    const int rl   = lane & 15;          // row-in-frag (A) / col-in-frag (B,C)
    const int ks   = lane >> 4;          // k-slot

    facc4 acc[4][4] = {};                // [row-frag m][gate]

    lstm_phase_lds<KX>(xt, Wx, As, Bs, acc, rb_blk, jb_blk, wr, wc, rl, ks, tid, n);
    lstm_phase_lds<Hdim>(h_in, Wh, As, Bs, acc, rb_blk, jb_blk, wr, wc, rl, ks, tid, n);

    // epilogue: C layout col=lane&15, row=(lane>>4)*4+j  [m89-verified]
    const int rb = rb_blk + wr * 64;
    const int jj = jb_blk + wc * 16 + rl;
    const float bi = bias[jj];
    const float bf_ = bias[Hdim + jj];
    const float bg = bias[2 * Hdim + jj];
    const float bo = bias[3 * Hdim + jj];
    #pragma unroll
    for (int m = 0; m < 4; ++m) {
        #pragma unroll
        for (int j = 0; j < 4; ++j) {
            const int r = rb + m * 16 + ks * 4 + j;
            if (r < n) {
                const size_t idx = (size_t)r * Hdim + jj;
                const float zi = acc[m][0][j] + bi;
                const float zf = acc[m][1][j] + bf_;
                const float zg = acc[m][2][j] + bg;
                const float zo = acc[m][3][j] + bo;
                const float co = c_state[idx];
                const float cn = sigf(zf) * co + sigf(zi) * tanh_fast(zg);
                c_state[idx] = cn;
                const float h = sigf(zo) * tanh_fast(cn);
                h_out[idx] = f2bf(h);
                if (h_f32 != nullptr) h_f32[idx] = h;
            }
        }
    }
}

// Paired launch: z==0 -> layer0 step t (t<Tdim); z==1 -> layer1 step t-1 (t>=1).
__global__ __launch_bounds__(256)
void lstm_pair_kernel(const ushort_t* __restrict__ xt,
                      const ushort_t* __restrict__ h0_in, ushort_t* __restrict__ h0_out,
                      float* __restrict__ c0,
                      const ushort_t* __restrict__ Wx0, const ushort_t* __restrict__ Wh0,
                      const float* __restrict__ b0,
                      const ushort_t* __restrict__ h1_in, ushort_t* __restrict__ h1_out,
                      float* __restrict__ c1,
                      const ushort_t* __restrict__ Wx1, const ushort_t* __restrict__ Wh1,
                      const float* __restrict__ b1,
                      float* __restrict__ temporal_or_null, int t, int n)
{
    __shared__ ushort_t As[128 * 32];
    __shared__ ushort_t Bs[128 * 32];
    if (blockIdx.z == 0) {
        if (t >= Tdim) return;
        lstm_step_core<Fdim>(xt, h0_in, c0, Wx0, Wh0, b0, h0_out, nullptr,
                             As, Bs, n, blockIdx.x, blockIdx.y);
    } else {
        if (t == 0) return;
        lstm_step_core<Hdim>(h0_in, h1_in, c1, Wx1, Wh1, b1, h1_out, temporal_or_null,
                             As, Bs, n, blockIdx.x, blockIdx.y);
    }
}

// ---------------- plain GEMM: C[n x 128] = A[n x 128] @ B[128 x 128] ----------------
__global__ __launch_bounds__(256)
void gemm_h_kernel(const float* __restrict__ A, const float* __restrict__ B,
                   float* __restrict__ C, int n)
{
    __shared__ float As[32][68];
    __shared__ float Bs[32][128];
    const int tid = threadIdx.x;
    const int jx = tid & 31;
    const int ry = tid >> 5;
    const int rowbase = blockIdx.x * 64;
    float acc[8][4];
    #pragma unroll
    for (int r = 0; r < 8; ++r)
        #pragma unroll
        for (int q = 0; q < 4; ++q) acc[r][q] = 0.f;

    for (int k0 = 0; k0 < 128; k0 += 32) {
        {
            const int kq = tid & 7, row = tid >> 3;
            #pragma unroll
            for (int hh = 0; hh < 2; ++hh) {
                const int r = row + hh * 32;
                const int grow = rowbase + r;
                float4 v = make_float4(0.f, 0.f, 0.f, 0.f);
                if (grow < n) v = *reinterpret_cast<const float4*>(
                                    A + (size_t)grow * 128 + k0 + kq * 4);
                As[kq*4+0][r] = v.x; As[kq*4+1][r] = v.y;
                As[kq*4+2][r] = v.z; As[kq*4+3][r] = v.w;
            }
        }
        {
            const float4* src = reinterpret_cast<const float4*>(B + (size_t)k0 * 128);
            float4* dst = reinterpret_cast<float4*>(&Bs[0][0]);
            for (int i = tid; i < 1024; i += 256) dst[i] = src[i];
        }
        __syncthreads();
        #pragma unroll
        for (int k = 0; k < 32; ++k) {
            float a[8];
            float4 a0 = *reinterpret_cast<const float4*>(&As[k][ry * 8]);
            float4 a1 = *reinterpret_cast<const float4*>(&As[k][ry * 8 + 4]);
            a[0]=a0.x; a[1]=a0.y; a[2]=a0.z; a[3]=a0.w;
            a[4]=a1.x; a[5]=a1.y; a[6]=a1.z; a[7]=a1.w;
            const float b0 = Bs[k][jx], b1 = Bs[k][jx+32];
            const float b2 = Bs[k][jx+64], b3 = Bs[k][jx+96];
            #pragma unroll
            for (int r = 0; r < 8; ++r) {
                acc[r][0] = fmaf(a[r], b0, acc[r][0]);
                acc[r][1] = fmaf(a[r], b1, acc[r][1]);
                acc[r][2] = fmaf(a[r], b2, acc[r][2]);
                acc[r][3] = fmaf(a[r], b3, acc[r][3]);
            }
        }
        __syncthreads();
    }
    #pragma unroll
    for (int r = 0; r < 8; ++r) {
        const int grow = rowbase + ry * 8 + r;
        if (grow < n) {
            #pragma unroll
            for (int q = 0; q < 4; ++q)
                C[(size_t)grow * 128 + jx + q * 32] = acc[r][q];
        }
    }
}

// ---------------- CSR build ----------------
__global__ __launch_bounds__(256)
void deg_hist_kernel(const int* __restrict__ dst, const float* __restrict__ w,
                     float* deg, int* counts, int E) {
    int e = blockIdx.x * 256 + threadIdx.x;
    if (e < E) {
        int d = dst[e];
        atomicAdd(&deg[d], w[e]);
        atomicAdd(&counts[d], 1);
    }
}

__global__ __launch_bounds__(256)
void dinv_kernel(float* deg_dinv, int n) {
    int i = blockIdx.x * 256 + threadIdx.x;
    if (i < n) deg_dinv[i] = rsqrtf(deg_dinv[i] + 1.0f);  // +1 = self-loop
}

__global__ __launch_bounds__(256)
void scan1_kernel(const int* __restrict__ counts, int* __restrict__ Sloc,
                  int* __restrict__ bsum, int n) {
    __shared__ int tmp[256];
    const int i = blockIdx.x * 256 + threadIdx.x;
    tmp[threadIdx.x] = (i < n) ? counts[i] : 0;
    __syncthreads();
    #pragma unroll
    for (int off = 1; off < 256; off <<= 1) {
        int t = (threadIdx.x >= off) ? tmp[threadIdx.x - off] : 0;
        __syncthreads();
        tmp[threadIdx.x] += t;
        __syncthreads();
    }
    if (i < n) Sloc[i] = tmp[threadIdx.x];
    if (threadIdx.x == 255) bsum[blockIdx.x] = tmp[255];
}

__global__ __launch_bounds__(256)
void scan2_kernel(int* __restrict__ bsum, int nb) {
    __shared__ int tmp[256];
    tmp[threadIdx.x] = (threadIdx.x < nb) ? bsum[threadIdx.x] : 0;
    __syncthreads();
    #pragma unroll
    for (int off = 1; off < 256; off <<= 1) {
        int t = (threadIdx.x >= off) ? tmp[threadIdx.x - off] : 0;
        __syncthreads();
        tmp[threadIdx.x] += t;
        __syncthreads();
    }
    if (threadIdx.x < nb) bsum[threadIdx.x] = tmp[threadIdx.x];
}

__global__ __launch_bounds__(256)
void scan3_kernel(const int* __restrict__ Sloc, const int* __restrict__ bsum,
                  const int* __restrict__ counts,
                  int* __restrict__ rowstart, int* __restrict__ running, int n) {
    const int i = blockIdx.x * 256 + threadIdx.x;
    if (i >= n) return;
    const int S = Sloc[i] + (blockIdx.x > 0 ? bsum[blockIdx.x - 1] : 0);
    const int rs = S - counts[i];
    rowstart[i] = rs;
    running[i]  = rs;
}

__global__ __launch_bounds__(256)
void scatter_kernel(const int* __restrict__ src, const int* __restrict__ dst,
                    const float* __restrict__ w, const float* __restrict__ dinv,
                    int* __restrict__ running,
                    int* __restrict__ s_srt, float* __restrict__ w_srt, int E) {
    int e = blockIdx.x * 256 + threadIdx.x;
    if (e >= E) return;
    const int s = src[e], d = dst[e];
    const int pos = atomicAdd(&running[d], 1);
    s_srt[pos] = s;
    w_srt[pos] = dinv[s] * w[e] * dinv[d];
}

// ---------------- fused gather + bias + self-loop + LayerNorm (+ReLU) ----------------
template<bool RELU>
__global__ __launch_bounds__(256)
void gather_ln_kernel(const float* __restrict__ hlin,
                      const int* __restrict__ rowstart, const int* __restrict__ counts,
                      const int* __restrict__ s_srt, const float* __restrict__ w_srt,
                      const float* __restrict__ dinv, const float* __restrict__ bias,
                      const float* __restrict__ gamma, const float* __restrict__ beta,
                      float* __restrict__ out, int n)
{
    const int wave = threadIdx.x >> 6;
    const int lane = threadIdx.x & 63;
    const int node = blockIdx.x * 4 + wave;
    if (node >= n) return;

    const float di = dinv[node];
    float a0 = hlin[(size_t)node * Hdim + lane]      * di * di + bias[lane];
    float a1 = hlin[(size_t)node * Hdim + 64 + lane] * di * di + bias[64 + lane];

    const int rs  = rowstart[node];
    const int cnt = counts[node];
    int j = rs;
    const int jend = rs + cnt;
    for (; j + 1 < jend; j += 2) {
        const int   sA = s_srt[j],     sB = s_srt[j + 1];
        const float wA = w_srt[j],     wB = w_srt[j + 1];
        const float* rA = hlin + (size_t)sA * Hdim;
        const float* rB = hlin + (size_t)sB * Hdim;
        a0 += rA[lane] * wA;      a1 += rA[64 + lane] * wA;
        a0 += rB[lane] * wB;      a1 += rB[64 + lane] * wB;
    }
    if (j < jend) {
        const int   sA = s_srt[j];
        const float wA = w_srt[j];
        const float* rA = hlin + (size_t)sA * Hdim;
        a0 += rA[lane] * wA;      a1 += rA[64 + lane] * wA;
    }

    float s = a0 + a1;
    #pragma unroll
    for (int m = 32; m >= 1; m >>= 1) s += __shfl_xor(s, m);
    const float mu = s * (1.f / 128.f);
    const float d0 = a0 - mu, d1 = a1 - mu;
    float v = d0 * d0 + d1 * d1;
    #pragma unroll
    for (int m = 32; m >= 1; m >>= 1) v += __shfl_xor(v, m);
    const float rstd = rsqrtf(v * (1.f / 128.f) + 1e-5f);
    float y0 = d0 * rstd * gamma[lane]      + beta[lane];
    float y1 = d1 * rstd * gamma[64 + lane] + beta[64 + lane];
    if (RELU) { y0 = fmaxf(y0, 0.f); y1 = fmaxf(y1, 0.f); }
    out[(size_t)node * Hdim + lane]      = y0;
    out[(size_t)node * Hdim + 64 + lane] = y1;
}

// ---------------- predictor: thread-per-node, acc[64] in VGPRs ----------------
// Weight row addr is wave-uniform (induction k, literal l) -> s_load path;
// fma is v_fma_f32 vgpr,vgpr,sgpr. 819M FMA -> ~10-15 us VALU floor.
__global__ __launch_bounds__(256)
void predictor_kernel(const float* __restrict__ temporal, const float* __restrict__ gfeat,
                      const float* __restrict__ Wp1, const float* __restrict__ bp1,
                      const float* __restrict__ Wp2, const float* __restrict__ bp2,
                      float* __restrict__ out, int n)
{
    const int node = blockIdx.x * 256 + threadIdx.x;
    const int nd = node < n ? node : n - 1;
    float acc[64];
    #pragma unroll
    for (int l = 0; l < 64; ++l) acc[l] = bp1[l];
    #pragma unroll
    for (int half = 0; half < 2; ++half) {
        const float* src = (half == 0 ? temporal : gfeat) + (size_t)nd * 128;
        const float* Wh_ = Wp1 + half * 128 * 64;
        for (int k4 = 0; k4 < 32; ++k4) {
            const float4 f = reinterpret_cast<const float4*>(src)[k4];
            const float fe[4] = { f.x, f.y, f.z, f.w };
            #pragma unroll
            for (int e = 0; e < 4; ++e) {
                const float* wr = Wh_ + (k4 * 4 + e) * 64;
                #pragma unroll
                for (int l = 0; l < 64; ++l)
                    acc[l] = fmaf(fe[e], wr[l], acc[l]);
            }
        }
    }
    float p = bp2[0];
    #pragma unroll
    for (int l = 0; l < 64; ++l)
        p = fmaf(fmaxf(acc[l], 0.f), Wp2[l], p);
    if (node < n) out[node] = p;
}

extern "C" void kernel_launch(void* const* d_in, const int* in_sizes, int n_in,
                              void* d_out, int out_size, void* d_ws, size_t ws_size,
                              hipStream_t stream) {
    const float* x    = (const float*)d_in[0];
    const int*   ei   = (const int*)d_in[1];
    const float* ew   = (const float*)d_in[2];
    const float* Wih0 = (const float*)d_in[3];
    const float* Whh0 = (const float*)d_in[4];
    const float* bih0 = (const float*)d_in[5];
    const float* bhh0 = (const float*)d_in[6];
    const float* Wih1 = (const float*)d_in[7];
    const float* Whh1 = (const float*)d_in[8];
    const float* bih1 = (const float*)d_in[9];
    const float* bhh1 = (const float*)d_in[10];
    const float* Wg1  = (const float*)d_in[11];
    const float* bg1  = (const float*)d_in[12];
    const float* g1   = (const float*)d_in[13];
    const float* be1  = (const float*)d_in[14];
    const float* Wg2  = (const float*)d_in[15];
    const float* bg2  = (const float*)d_in[16];
    const float* g2   = (const float*)d_in[17];
    const float* be2  = (const float*)d_in[18];
    const float* Wp1  = (const float*)d_in[19];
    const float* bp1  = (const float*)d_in[20];
    const float* Wp2  = (const float*)d_in[21];
    const float* bp2  = (const float*)d_in[22];
    float* out = (float*)d_out;

    const int n = in_sizes[0] / (Fdim * Tdim);
    const int E = in_sizes[1] / 2;
    const int* esrc = ei;
    const int* edst = ei + E;

    const size_t NH = (size_t)n * Hdim;
    const size_t NF = (size_t)n * Fdim;

    // ---- workspace layout (byte bump-allocator, 256B aligned) ----
    const size_t wsz_weights = (size_t)(512 * Fdim + 3 * 512 * Hdim) * 2;
    const size_t csr_bytes = (size_t)n * 16 + (size_t)E * 8 + 2048;
    const size_t need_rest = 4 * (NH * 2)
                           + 2 * (NH * 4)
                           + (NH * 4)
                           + (size_t)n * 4
                           + wsz_weights + 2 * 512 * 4 + csr_bytes + 16384;
    const bool use_xs = ws_size >= NF * Tdim * 2 + need_rest;

    char* base = (char*)d_ws;
    size_t off = 0;
    auto alloc = [&](size_t bytes) -> char* {
        off = (off + 255) & ~(size_t)255;
        char* p = base + off;
        off += bytes;
        return p;
    };
    ushort_t* xs   = (ushort_t*)alloc(use_xs ? NF * Tdim * 2 : NF * 2);
    ushort_t* h0a  = (ushort_t*)alloc(NH * 2);
    ushort_t* h0b  = (ushort_t*)alloc(NH * 2);
    ushort_t* h1a  = (ushort_t*)alloc(NH * 2);
    ushort_t* h1b  = (ushort_t*)alloc(NH * 2);
    float*    c0   = (float*)alloc(NH * 4);
    float*    c1   = (float*)alloc(NH * 4);
    float*    temporal = (float*)alloc(NH * 4);
    float*    dinv = (float*)alloc((size_t)n * 4);
    ushort_t* Wx0b = (ushort_t*)alloc((size_t)512 * Fdim * 2);
    ushort_t* Wh0b = (ushort_t*)alloc((size_t)512 * Hdim * 2);
    ushort_t* Wx1b = (ushort_t*)alloc((size_t)512 * Hdim * 2);
    ushort_t* Wh1b = (ushort_t*)alloc((size_t)512 * Hdim * 2);
    float*    bias0 = (float*)alloc(512 * 4);
    float*    bias1 = (float*)alloc(512 * 4);
    int*   counts   = (int*)alloc((size_t)n * 4);
    int*   Sloc     = (int*)alloc((size_t)n * 4);
    int*   bsum     = (int*)alloc(1024);
    int*   rowstart = (int*)alloc((size_t)n * 4);
    int*   running  = (int*)alloc((size_t)n * 4);
    int*   s_srt    = (int*)alloc((size_t)E * 4);
    float* w_srt    = (float*)alloc((size_t)E * 4);
    // graph-phase scratch aliases the LSTM-dead region at the base
    float* G1 = (float*)base;
    float* G2 = G1 + NH;
    float* G3 = G2 + NH;

    // ---- weight/bias prep ----
    {
        const int n0 = 512 * Fdim, n1 = 512 * Hdim;
        cvt_bf16_kernel<<<(n0/4 + 255)/256, 256, 0, stream>>>(Wih0, Wx0b, n0);
        cvt_bf16_kernel<<<(n1/4 + 255)/256, 256, 0, stream>>>(Whh0, Wh0b, n1);
        cvt_bf16_kernel<<<(n1/4 + 255)/256, 256, 0, stream>>>(Wih1, Wx1b, n1);
        cvt_bf16_kernel<<<(n1/4 + 255)/256, 256, 0, stream>>>(Whh1, Wh1b, n1);
        bias_add_kernel<<<2, 256, 0, stream>>>(bih0, bhh0, bias0, 512);
        bias_add_kernel<<<2, 256, 0, stream>>>(bih1, bhh1, bias1, 512);
    }

    hipMemsetAsync(h0a, 0, NH * 2, stream);
    hipMemsetAsync(h1a, 0, NH * 2, stream);
    hipMemsetAsync(c0, 0, NH * 4, stream);
    hipMemsetAsync(c1, 0, NH * 4, stream);
    hipMemsetAsync(dinv, 0, (size_t)n * 4, stream);
    hipMemsetAsync(counts, 0, (size_t)n * 4, stream);

    // ---- CSR build (graph shared by both GCN layers) ----
    {
        const int eb = (E + 255) / 256;
        const int nb = (n + 255) / 256;
        deg_hist_kernel<<<eb, 256, 0, stream>>>(edst, ew, dinv, counts, E);
        dinv_kernel<<<nb, 256, 0, stream>>>(dinv, n);
        scan1_kernel<<<nb, 256, 0, stream>>>(counts, Sloc, bsum, n);
        scan2_kernel<<<1, 256, 0, stream>>>(bsum, nb);
        scan3_kernel<<<nb, 256, 0, stream>>>(Sloc, bsum, counts, rowstart, running, n);
        scatter_kernel<<<eb, 256, 0, stream>>>(esrc, edst, ew, dinv, running,
                                               s_srt, w_srt, E);
    }

    if (use_xs)
        transpose_x_kernel<<<(int)((NF + 255) / 256), 256, 0, stream>>>(x, xs, (int)NF);

    // ---- LSTM: 17 paired launches (L0 step t || L1 step t-1) ----
    ushort_t* B[2] = { h0a, h0b };
    ushort_t* H[2] = { h1a, h1b };
    dim3 lgrid((n + 127) / 128, 4, 2);
    for (int t = 0; t <= Tdim; ++t) {
        const ushort_t* xt = xs;
        if (t < Tdim) {
            if (use_xs) xt = xs + (size_t)t * NF;
            else {
                xslice_kernel<<<(int)((NF + 255) / 256), 256, 0, stream>>>(x, xs, t, n);
                xt = xs;
            }
        }
        float* tf32 = (t == Tdim) ? temporal : nullptr;
        lstm_pair_kernel<<<lgrid, 256, 0, stream>>>(
            xt, B[t & 1], B[(t + 1) & 1], c0, Wx0b, Wh0b, bias0,
            H[(t + 1) & 1], H[t & 1], c1, Wx1b, Wh1b, bias1,
            tf32, t, n);
    }

    // ---- graph encoder: gemm -> fused gather+LN(+ReLU) ----
    const int gblocks  = (n + 63) / 64;
    const int nwblocks = (n + 3) / 4;
    gemm_h_kernel<<<gblocks, 256, 0, stream>>>(temporal, Wg1, G1, n);
    gather_ln_kernel<true><<<nwblocks, 256, 0, stream>>>(
        G1, rowstart, counts, s_srt, w_srt, dinv, bg1, g1, be1, G3, n);
    gemm_h_kernel<<<gblocks, 256, 0, stream>>>(G3, Wg2, G1, n);
    gather_ln_kernel<false><<<nwblocks, 256, 0, stream>>>(
        G1, rowstart, counts, s_srt, w_srt, dinv, bg2, g2, be2, G2, n);

    // ---- predictor ----
    predictor_kernel<<<(n + 255) / 256, 256, 0, stream>>>(
        temporal, G2, Wp1, bp1, Wp2, bp2, out, n);
}

// Round 7
// 1761.399 us; speedup vs baseline: 4.4523x; 1.0167x over previous
//
#include <hip/hip_runtime.h>
#include <math.h>

#define Hdim 128
#define Fdim 32
#define Tdim 16

typedef short  bfrag8 __attribute__((ext_vector_type(8)));
typedef float  facc4  __attribute__((ext_vector_type(4)));
typedef unsigned short ushort_t;

__device__ __forceinline__ float sigf(float x) {
    return 1.0f / (1.0f + __expf(-x));
}
__device__ __forceinline__ float tanh_fast(float x) {
    x = fminf(fmaxf(x, -15.f), 15.f);
    float e = __expf(2.f * x);
    return (e - 1.f) / (e + 1.f);
}
__device__ __forceinline__ ushort_t f2bf(float f) {
    union { float f; unsigned u; } v; v.f = f;
    unsigned u = v.u;
    unsigned r = u + 0x7fffu + ((u >> 16) & 1u);   // RNE
    return (ushort_t)(r >> 16);
}

// async global->LDS, 16B per lane; LDS dest = wave-uniform base + lane*16
typedef __attribute__((address_space(3))) unsigned int lds_uint;
typedef __attribute__((address_space(1))) const unsigned int glob_uint;
__device__ __forceinline__ void gload_lds16(const ushort_t* g, ushort_t* l) {
    __builtin_amdgcn_global_load_lds((glob_uint*)g, (lds_uint*)l, 16, 0, 0);
}

// ---------------- f32 -> bf16 convert (weights) ----------------
__global__ __launch_bounds__(256)
void cvt_bf16_kernel(const float* __restrict__ in, ushort_t* __restrict__ out, int nelem) {
    int i = (blockIdx.x * 256 + threadIdx.x) * 4;
    if (i < nelem) {
        float4 v = *reinterpret_cast<const float4*>(in + i);
        out[i + 0] = f2bf(v.x); out[i + 1] = f2bf(v.y);
        out[i + 2] = f2bf(v.z); out[i + 3] = f2bf(v.w);
    }
}

__global__ __launch_bounds__(256)
void bias_add_kernel(const float* __restrict__ a, const float* __restrict__ b,
                     float* __restrict__ out, int n) {
    int i = blockIdx.x * 256 + threadIdx.x;
    if (i < n) out[i] = a[i] + b[i];
}

// ---------------- x (N,F,T) f32 -> xs (T,N,F) bf16 ----------------
__global__ __launch_bounds__(256)
void transpose_x_kernel(const float* __restrict__ x, ushort_t* __restrict__ xs, int nf) {
    int tid = blockIdx.x * 256 + threadIdx.x;  // over N*F
    if (tid >= nf) return;
    const float4* src = reinterpret_cast<const float4*>(x + (size_t)tid * Tdim);
    float4 a = src[0], b = src[1], c = src[2], d = src[3];
    float v[16] = {a.x,a.y,a.z,a.w, b.x,b.y,b.z,b.w, c.x,c.y,c.z,c.w, d.x,d.y,d.z,d.w};
    #pragma unroll
    for (int t = 0; t < Tdim; ++t) xs[(size_t)t * nf + tid] = f2bf(v[t]);
}

// fallback: extract slice t of x -> xt (N,F) bf16
__global__ __launch_bounds__(256)
void xslice_kernel(const float* __restrict__ x, ushort_t* __restrict__ xt, int t, int n) {
    int idx = blockIdx.x * 256 + threadIdx.x;
    if (idx < n * Fdim) {
        int node = idx >> 5, f = idx & 31;
        xt[idx] = f2bf(x[(size_t)node * (Fdim * Tdim) + f * Tdim + t]);
    }
}

// ---------------- MFMA LSTM step (async dbuf LDS staging) ----------------
// Block: 128 rows x 32 jj x 4 gates. 4 waves (2 row x 2 jj).
// Unified iteration space: gi < KX/32 -> (xt,Wx); else -> (h_in,Wh).
// Per iter: stage gi+1 tiles (global_load_lds, dbuf) || ds_read+MFMA on gi;
// one __syncthreads per iter (its implicit vmcnt(0) drains the async loads).
template<int KX>
__device__ __forceinline__
void get_iter(int gi, const ushort_t* xt, const ushort_t* h_in,
              const ushort_t* Wx, const ushort_t* Wh,
              const ushort_t*& Ap, const ushort_t*& Wp, int& Kp, int& k0)
{
    constexpr int itX = KX / 32;
    if (gi < itX) { Ap = xt;   Wp = Wx; Kp = KX;   k0 = gi * 32; }
    else          { Ap = h_in; Wp = Wh; Kp = Hdim; k0 = (gi - itX) * 32; }
}

template<int KX>
__device__ __forceinline__
void lstm_step_core(const ushort_t* __restrict__ xt, const ushort_t* __restrict__ h_in,
                    float* __restrict__ c_state,
                    const ushort_t* __restrict__ Wx, const ushort_t* __restrict__ Wh,
                    const float* __restrict__ bias,
                    ushort_t* __restrict__ h_out, float* __restrict__ h_f32,
                    ushort_t (*As)[4096], ushort_t (*Bs)[4096],
                    int n, int bx, int by)
{
    constexpr int NIT = KX / 32 + 4;
    const int tid  = threadIdx.x;
    const int lane = tid & 63;
    const int w    = tid >> 6;
    const int wr   = w >> 1, wc = w & 1;
    const int rb_blk = bx * 128;
    const int jb_blk = by * 32;
    const int rl   = lane & 15;          // row-in-frag (A) / col-in-frag (B,C)
    const int ks   = lane >> 4;          // k-slot
    const int sub  = lane >> 2;          // staging: row-in-16
    const int boff = (lane & 3) * 8;     // staging: ushort offset (16B granules)

    auto stage = [&](int gi, int b) {
        const ushort_t *Ap, *Wp; int Kp, k0;
        get_iter<KX>(gi, xt, h_in, Wx, Wh, Ap, Wp, Kp, k0);
        #pragma unroll
        for (int h = 0; h < 2; ++h) {
            const int r = w * 32 + h * 16 + sub;            // 0..127
            int growA = rb_blk + r; growA = growA < n ? growA : n - 1;
            gload_lds16(Ap + (size_t)growA * Kp + k0 + boff,
                        As[b] + (w * 32 + h * 16) * 32);
            const int g = r >> 5, j = r & 31;               // z-row -> (gate,jj)
            gload_lds16(Wp + (size_t)(g * Hdim + jb_blk + j) * Kp + k0 + boff,
                        Bs[b] + (w * 32 + h * 16) * 32);
        }
    };

    facc4 acc[4][4] = {};                // [row-frag m][gate]

    stage(0, 0);
    __syncthreads();
    #pragma unroll
    for (int gi = 0; gi < NIT; ++gi) {
        const int cur = gi & 1;
        if (gi + 1 < NIT) stage(gi + 1, cur ^ 1);
        bfrag8 bfr[4];
        #pragma unroll
        for (int g = 0; g < 4; ++g)
            bfr[g] = *reinterpret_cast<const bfrag8*>(
                Bs[cur] + ((g * 32 + wc * 16 + rl) * 32 + ks * 8));
        #pragma unroll
        for (int m = 0; m < 4; ++m) {
            bfrag8 afr = *reinterpret_cast<const bfrag8*>(
                As[cur] + ((wr * 64 + m * 16 + rl) * 32 + ks * 8));
            #pragma unroll
            for (int g = 0; g < 4; ++g)
                acc[m][g] = __builtin_amdgcn_mfma_f32_16x16x32_bf16(
                    afr, bfr[g], acc[m][g], 0, 0, 0);
        }
        __syncthreads();   // drains this iter's ds_reads AND next-iter staging
    }

    // epilogue: C layout col=lane&15, row=(lane>>4)*4+j  [m89-verified]
    const int rb = rb_blk + wr * 64;
    const int jj = jb_blk + wc * 16 + rl;
    const float bi = bias[jj];
    const float bf_ = bias[Hdim + jj];
    const float bg = bias[2 * Hdim + jj];
    const float bo = bias[3 * Hdim + jj];
    #pragma unroll
    for (int m = 0; m < 4; ++m) {
        #pragma unroll
        for (int j = 0; j < 4; ++j) {
            const int r = rb + m * 16 + ks * 4 + j;
            if (r < n) {
                const size_t idx = (size_t)r * Hdim + jj;
                const float zi = acc[m][0][j] + bi;
                const float zf = acc[m][1][j] + bf_;
                const float zg = acc[m][2][j] + bg;
                const float zo = acc[m][3][j] + bo;
                const float co = c_state[idx];
                const float cn = sigf(zf) * co + sigf(zi) * tanh_fast(zg);
                c_state[idx] = cn;
                const float h = sigf(zo) * tanh_fast(cn);
                h_out[idx] = f2bf(h);
                if (h_f32 != nullptr) h_f32[idx] = h;
            }
        }
    }
}

// Paired launch: z==0 -> layer0 step t (t<Tdim); z==1 -> layer1 step t-1 (t>=1).
__global__ __launch_bounds__(256)
void lstm_pair_kernel(const ushort_t* __restrict__ xt,
                      const ushort_t* __restrict__ h0_in, ushort_t* __restrict__ h0_out,
                      float* __restrict__ c0,
                      const ushort_t* __restrict__ Wx0, const ushort_t* __restrict__ Wh0,
                      const float* __restrict__ b0,
                      const ushort_t* __restrict__ h1_in, ushort_t* __restrict__ h1_out,
                      float* __restrict__ c1,
                      const ushort_t* __restrict__ Wx1, const ushort_t* __restrict__ Wh1,
                      const float* __restrict__ b1,
                      float* __restrict__ temporal_or_null, int t, int n)
{
    __shared__ ushort_t As[2][4096];
    __shared__ ushort_t Bs[2][4096];
    if (blockIdx.z == 0) {
        if (t >= Tdim) return;
        lstm_step_core<Fdim>(xt, h0_in, c0, Wx0, Wh0, b0, h0_out, nullptr,
                             As, Bs, n, blockIdx.x, blockIdx.y);
    } else {
        if (t == 0) return;
        lstm_step_core<Hdim>(h0_in, h1_in, c1, Wx1, Wh1, b1, h1_out, temporal_or_null,
                             As, Bs, n, blockIdx.x, blockIdx.y);
    }
}

// ---------------- plain GEMM: C[n x 128] = A[n x 128] @ B[128 x 128] ----------------
__global__ __launch_bounds__(256)
void gemm_h_kernel(const float* __restrict__ A, const float* __restrict__ B,
                   float* __restrict__ C, int n)
{
    __shared__ float As[32][68];
    __shared__ float Bs[32][128];
    const int tid = threadIdx.x;
    const int jx = tid & 31;
    const int ry = tid >> 5;
    const int rowbase = blockIdx.x * 64;
    float acc[8][4];
    #pragma unroll
    for (int r = 0; r < 8; ++r)
        #pragma unroll
        for (int q = 0; q < 4; ++q) acc[r][q] = 0.f;

    for (int k0 = 0; k0 < 128; k0 += 32) {
        {
            const int kq = tid & 7, row = tid >> 3;
            #pragma unroll
            for (int hh = 0; hh < 2; ++hh) {
                const int r = row + hh * 32;
                const int grow = rowbase + r;
                float4 v = make_float4(0.f, 0.f, 0.f, 0.f);
                if (grow < n) v = *reinterpret_cast<const float4*>(
                                    A + (size_t)grow * 128 + k0 + kq * 4);
                As[kq*4+0][r] = v.x; As[kq*4+1][r] = v.y;
                As[kq*4+2][r] = v.z; As[kq*4+3][r] = v.w;
            }
        }
        {
            const float4* src = reinterpret_cast<const float4*>(B + (size_t)k0 * 128);
            float4* dst = reinterpret_cast<float4*>(&Bs[0][0]);
            for (int i = tid; i < 1024; i += 256) dst[i] = src[i];
        }
        __syncthreads();
        #pragma unroll
        for (int k = 0; k < 32; ++k) {
            float a[8];
            float4 a0 = *reinterpret_cast<const float4*>(&As[k][ry * 8]);
            float4 a1 = *reinterpret_cast<const float4*>(&As[k][ry * 8 + 4]);
            a[0]=a0.x; a[1]=a0.y; a[2]=a0.z; a[3]=a0.w;
            a[4]=a1.x; a[5]=a1.y; a[6]=a1.z; a[7]=a1.w;
            const float b0 = Bs[k][jx], b1 = Bs[k][jx+32];
            const float b2 = Bs[k][jx+64], b3 = Bs[k][jx+96];
            #pragma unroll
            for (int r = 0; r < 8; ++r) {
                acc[r][0] = fmaf(a[r], b0, acc[r][0]);
                acc[r][1] = fmaf(a[r], b1, acc[r][1]);
                acc[r][2] = fmaf(a[r], b2, acc[r][2]);
                acc[r][3] = fmaf(a[r], b3, acc[r][3]);
            }
        }
        __syncthreads();
    }
    #pragma unroll
    for (int r = 0; r < 8; ++r) {
        const int grow = rowbase + ry * 8 + r;
        if (grow < n) {
            #pragma unroll
            for (int q = 0; q < 4; ++q)
                C[(size_t)grow * 128 + jx + q * 32] = acc[r][q];
        }
    }
}

// ---------------- CSR build ----------------
__global__ __launch_bounds__(256)
void deg_hist_kernel(const int* __restrict__ dst, const float* __restrict__ w,
                     float* deg, int* counts, int E) {
    int e = blockIdx.x * 256 + threadIdx.x;
    if (e < E) {
        int d = dst[e];
        atomicAdd(&deg[d], w[e]);
        atomicAdd(&counts[d], 1);
    }
}

__global__ __launch_bounds__(256)
void dinv_kernel(float* deg_dinv, int n) {
    int i = blockIdx.x * 256 + threadIdx.x;
    if (i < n) deg_dinv[i] = rsqrtf(deg_dinv[i] + 1.0f);  // +1 = self-loop
}

__global__ __launch_bounds__(256)
void scan1_kernel(const int* __restrict__ counts, int* __restrict__ Sloc,
                  int* __restrict__ bsum, int n) {
    __shared__ int tmp[256];
    const int i = blockIdx.x * 256 + threadIdx.x;
    tmp[threadIdx.x] = (i < n) ? counts[i] : 0;
    __syncthreads();
    #pragma unroll
    for (int off = 1; off < 256; off <<= 1) {
        int t = (threadIdx.x >= off) ? tmp[threadIdx.x - off] : 0;
        __syncthreads();
        tmp[threadIdx.x] += t;
        __syncthreads();
    }
    if (i < n) Sloc[i] = tmp[threadIdx.x];
    if (threadIdx.x == 255) bsum[blockIdx.x] = tmp[255];
}

__global__ __launch_bounds__(256)
void scan2_kernel(int* __restrict__ bsum, int nb) {
    __shared__ int tmp[256];
    tmp[threadIdx.x] = (threadIdx.x < nb) ? bsum[threadIdx.x] : 0;
    __syncthreads();
    #pragma unroll
    for (int off = 1; off < 256; off <<= 1) {
        int t = (threadIdx.x >= off) ? tmp[threadIdx.x - off] : 0;
        __syncthreads();
        tmp[threadIdx.x] += t;
        __syncthreads();
    }
    if (threadIdx.x < nb) bsum[threadIdx.x] = tmp[threadIdx.x];
}

__global__ __launch_bounds__(256)
void scan3_kernel(const int* __restrict__ Sloc, const int* __restrict__ bsum,
                  const int* __restrict__ counts,
                  int* __restrict__ rowstart, int* __restrict__ running, int n) {
    const int i = blockIdx.x * 256 + threadIdx.x;
    if (i >= n) return;
    const int S = Sloc[i] + (blockIdx.x > 0 ? bsum[blockIdx.x - 1] : 0);
    const int rs = S - counts[i];
    rowstart[i] = rs;
    running[i]  = rs;
}

__global__ __launch_bounds__(256)
void scatter_kernel(const int* __restrict__ src, const int* __restrict__ dst,
                    const float* __restrict__ w, const float* __restrict__ dinv,
                    int* __restrict__ running,
                    int* __restrict__ s_srt, float* __restrict__ w_srt, int E) {
    int e = blockIdx.x * 256 + threadIdx.x;
    if (e >= E) return;
    const int s = src[e], d = dst[e];
    const int pos = atomicAdd(&running[d], 1);
    s_srt[pos] = s;
    w_srt[pos] = dinv[s] * w[e] * dinv[d];
}

// ---------------- fused gather + bias + self-loop + LayerNorm (+ReLU) ----------------
template<bool RELU>
__global__ __launch_bounds__(256)
void gather_ln_kernel(const float* __restrict__ hlin,
                      const int* __restrict__ rowstart, const int* __restrict__ counts,
                      const int* __restrict__ s_srt, const float* __restrict__ w_srt,
                      const float* __restrict__ dinv, const float* __restrict__ bias,
                      const float* __restrict__ gamma, const float* __restrict__ beta,
                      float* __restrict__ out, int n)
{
    const int wave = threadIdx.x >> 6;
    const int lane = threadIdx.x & 63;
    const int node = blockIdx.x * 4 + wave;
    if (node >= n) return;

    const float di = dinv[node];
    float a0 = hlin[(size_t)node * Hdim + lane]      * di * di + bias[lane];
    float a1 = hlin[(size_t)node * Hdim + 64 + lane] * di * di + bias[64 + lane];

    const int rs  = rowstart[node];
    const int cnt = counts[node];
    int j = rs;
    const int jend = rs + cnt;
    for (; j + 1 < jend; j += 2) {
        const int   sA = s_srt[j],     sB = s_srt[j + 1];
        const float wA = w_srt[j],     wB = w_srt[j + 1];
        const float* rA = hlin + (size_t)sA * Hdim;
        const float* rB = hlin + (size_t)sB * Hdim;
        a0 += rA[lane] * wA;      a1 += rA[64 + lane] * wA;
        a0 += rB[lane] * wB;      a1 += rB[64 + lane] * wB;
    }
    if (j < jend) {
        const int   sA = s_srt[j];
        const float wA = w_srt[j];
        const float* rA = hlin + (size_t)sA * Hdim;
        a0 += rA[lane] * wA;      a1 += rA[64 + lane] * wA;
    }

    float s = a0 + a1;
    #pragma unroll
    for (int m = 32; m >= 1; m >>= 1) s += __shfl_xor(s, m);
    const float mu = s * (1.f / 128.f);
    const float d0 = a0 - mu, d1 = a1 - mu;
    float v = d0 * d0 + d1 * d1;
    #pragma unroll
    for (int m = 32; m >= 1; m >>= 1) v += __shfl_xor(v, m);
    const float rstd = rsqrtf(v * (1.f / 128.f) + 1e-5f);
    float y0 = d0 * rstd * gamma[lane]      + beta[lane];
    float y1 = d1 * rstd * gamma[64 + lane] + beta[64 + lane];
    if (RELU) { y0 = fmaxf(y0, 0.f); y1 = fmaxf(y1, 0.f); }
    out[(size_t)node * Hdim + lane]      = y0;
    out[(size_t)node * Hdim + 64 + lane] = y1;
}

// ---------------- predictor: thread-per-node, Wp1 staged in LDS ----------------
// Inner reads are wave-uniform ds_read_b128 broadcasts (conflict-free);
// removes the per-k L2 scalar-load latency that bound the s_load version.
__global__ __launch_bounds__(256)
void predictor_kernel(const float* __restrict__ temporal, const float* __restrict__ gfeat,
                      const float* __restrict__ Wp1, const float* __restrict__ bp1,
                      const float* __restrict__ Wp2, const float* __restrict__ bp2,
                      float* __restrict__ out, int n)
{
    __shared__ float Ws[256 * 64];   // whole Wp1, 64 KiB
    const int tid = threadIdx.x;
    {
        const float4* src = reinterpret_cast<const float4*>(Wp1);
        float4* dst = reinterpret_cast<float4*>(Ws);
        for (int i = tid; i < 4096; i += 256) dst[i] = src[i];
    }
    __syncthreads();
    const int node = blockIdx.x * 256 + tid;
    const int nd = node < n ? node : n - 1;
    float acc[64];
    #pragma unroll
    for (int l = 0; l < 64; ++l) acc[l] = bp1[l];
    #pragma unroll
    for (int half = 0; half < 2; ++half) {
        const float* srcp = (half == 0 ? temporal : gfeat) + (size_t)nd * 128;
        #pragma unroll 4
        for (int k4 = 0; k4 < 32; ++k4) {
            const float4 f = reinterpret_cast<const float4*>(srcp)[k4];
            const float fe[4] = { f.x, f.y, f.z, f.w };
            #pragma unroll
            for (int e = 0; e < 4; ++e) {
                const float4* wrow = reinterpret_cast<const float4*>(
                    Ws + (half * 128 + k4 * 4 + e) * 64);
                #pragma unroll
                for (int l4 = 0; l4 < 16; ++l4) {
                    const float4 wv = wrow[l4];
                    acc[l4*4+0] = fmaf(fe[e], wv.x, acc[l4*4+0]);
                    acc[l4*4+1] = fmaf(fe[e], wv.y, acc[l4*4+1]);
                    acc[l4*4+2] = fmaf(fe[e], wv.z, acc[l4*4+2]);
                    acc[l4*4+3] = fmaf(fe[e], wv.w, acc[l4*4+3]);
                }
            }
        }
    }
    float p = bp2[0];
    #pragma unroll
    for (int l = 0; l < 64; ++l)
        p = fmaf(fmaxf(acc[l], 0.f), Wp2[l], p);
    if (node < n) out[node] = p;
}

extern "C" void kernel_launch(void* const* d_in, const int* in_sizes, int n_in,
                              void* d_out, int out_size, void* d_ws, size_t ws_size,
                              hipStream_t stream) {
    const float* x    = (const float*)d_in[0];
    const int*   ei   = (const int*)d_in[1];
    const float* ew   = (const float*)d_in[2];
    const float* Wih0 = (const float*)d_in[3];
    const float* Whh0 = (const float*)d_in[4];
    const float* bih0 = (const float*)d_in[5];
    const float* bhh0 = (const float*)d_in[6];
    const float* Wih1 = (const float*)d_in[7];
    const float* Whh1 = (const float*)d_in[8];
    const float* bih1 = (const float*)d_in[9];
    const float* bhh1 = (const float*)d_in[10];
    const float* Wg1  = (const float*)d_in[11];
    const float* bg1  = (const float*)d_in[12];
    const float* g1   = (const float*)d_in[13];
    const float* be1  = (const float*)d_in[14];
    const float* Wg2  = (const float*)d_in[15];
    const float* bg2  = (const float*)d_in[16];
    const float* g2   = (const float*)d_in[17];
    const float* be2  = (const float*)d_in[18];
    const float* Wp1  = (const float*)d_in[19];
    const float* bp1  = (const float*)d_in[20];
    const float* Wp2  = (const float*)d_in[21];
    const float* bp2  = (const float*)d_in[22];
    float* out = (float*)d_out;

    const int n = in_sizes[0] / (Fdim * Tdim);
    const int E = in_sizes[1] / 2;
    const int* esrc = ei;
    const int* edst = ei + E;

    const size_t NH = (size_t)n * Hdim;
    const size_t NF = (size_t)n * Fdim;

    // ---- workspace layout (byte bump-allocator, 256B aligned) ----
    const size_t wsz_weights = (size_t)(512 * Fdim + 3 * 512 * Hdim) * 2;
    const size_t csr_bytes = (size_t)n * 16 + (size_t)E * 8 + 2048;
    const size_t need_rest = 4 * (NH * 2)
                           + 2 * (NH * 4)
                           + (NH * 4)
                           + (size_t)n * 4
                           + wsz_weights + 2 * 512 * 4 + csr_bytes + 16384;
    const bool use_xs = ws_size >= NF * Tdim * 2 + need_rest;

    char* base = (char*)d_ws;
    size_t off = 0;
    auto alloc = [&](size_t bytes) -> char* {
        off = (off + 255) & ~(size_t)255;
        char* p = base + off;
        off += bytes;
        return p;
    };
    ushort_t* xs   = (ushort_t*)alloc(use_xs ? NF * Tdim * 2 : NF * 2);
    ushort_t* h0a  = (ushort_t*)alloc(NH * 2);
    ushort_t* h0b  = (ushort_t*)alloc(NH * 2);
    ushort_t* h1a  = (ushort_t*)alloc(NH * 2);
    ushort_t* h1b  = (ushort_t*)alloc(NH * 2);
    float*    c0   = (float*)alloc(NH * 4);
    float*    c1   = (float*)alloc(NH * 4);
    float*    temporal = (float*)alloc(NH * 4);
    float*    dinv = (float*)alloc((size_t)n * 4);
    ushort_t* Wx0b = (ushort_t*)alloc((size_t)512 * Fdim * 2);
    ushort_t* Wh0b = (ushort_t*)alloc((size_t)512 * Hdim * 2);
    ushort_t* Wx1b = (ushort_t*)alloc((size_t)512 * Hdim * 2);
    ushort_t* Wh1b = (ushort_t*)alloc((size_t)512 * Hdim * 2);
    float*    bias0 = (float*)alloc(512 * 4);
    float*    bias1 = (float*)alloc(512 * 4);
    int*   counts   = (int*)alloc((size_t)n * 4);
    int*   Sloc     = (int*)alloc((size_t)n * 4);
    int*   bsum     = (int*)alloc(1024);
    int*   rowstart = (int*)alloc((size_t)n * 4);
    int*   running  = (int*)alloc((size_t)n * 4);
    int*   s_srt    = (int*)alloc((size_t)E * 4);
    float* w_srt    = (float*)alloc((size_t)E * 4);
    // graph-phase scratch aliases the LSTM-dead region at the base
    float* G1 = (float*)base;
    float* G2 = G1 + NH;
    float* G3 = G2 + NH;

    // ---- weight/bias prep ----
    {
        const int n0 = 512 * Fdim, n1 = 512 * Hdim;
        cvt_bf16_kernel<<<(n0/4 + 255)/256, 256, 0, stream>>>(Wih0, Wx0b, n0);
        cvt_bf16_kernel<<<(n1/4 + 255)/256, 256, 0, stream>>>(Whh0, Wh0b, n1);
        cvt_bf16_kernel<<<(n1/4 + 255)/256, 256, 0, stream>>>(Wih1, Wx1b, n1);
        cvt_bf16_kernel<<<(n1/4 + 255)/256, 256, 0, stream>>>(Whh1, Wh1b, n1);
        bias_add_kernel<<<2, 256, 0, stream>>>(bih0, bhh0, bias0, 512);
        bias_add_kernel<<<2, 256, 0, stream>>>(bih1, bhh1, bias1, 512);
    }

    hipMemsetAsync(h0a, 0, NH * 2, stream);
    hipMemsetAsync(h1a, 0, NH * 2, stream);
    hipMemsetAsync(c0, 0, NH * 4, stream);
    hipMemsetAsync(c1, 0, NH * 4, stream);
    hipMemsetAsync(dinv, 0, (size_t)n * 4, stream);
    hipMemsetAsync(counts, 0, (size_t)n * 4, stream);

    // ---- CSR build (graph shared by both GCN layers) ----
    {
        const int eb = (E + 255) / 256;
        const int nb = (n + 255) / 256;
        deg_hist_kernel<<<eb, 256, 0, stream>>>(edst, ew, dinv, counts, E);
        dinv_kernel<<<nb, 256, 0, stream>>>(dinv, n);
        scan1_kernel<<<nb, 256, 0, stream>>>(counts, Sloc, bsum, n);
        scan2_kernel<<<1, 256, 0, stream>>>(bsum, nb);
        scan3_kernel<<<nb, 256, 0, stream>>>(Sloc, bsum, counts, rowstart, running, n);
        scatter_kernel<<<eb, 256, 0, stream>>>(esrc, edst, ew, dinv, running,
                                               s_srt, w_srt, E);
    }

    if (use_xs)
        transpose_x_kernel<<<(int)((NF + 255) / 256), 256, 0, stream>>>(x, xs, (int)NF);

    // ---- LSTM: 17 paired launches (L0 step t || L1 step t-1) ----
    ushort_t* B[2] = { h0a, h0b };
    ushort_t* H[2] = { h1a, h1b };
    dim3 lgrid((n + 127) / 128, 4, 2);
    for (int t = 0; t <= Tdim; ++t) {
        const ushort_t* xt = xs;
        if (t < Tdim) {
            if (use_xs) xt = xs + (size_t)t * NF;
            else {
                xslice_kernel<<<(int)((NF + 255) / 256), 256, 0, stream>>>(x, xs, t, n);
                xt = xs;
            }
        }
        float* tf32 = (t == Tdim) ? temporal : nullptr;
        lstm_pair_kernel<<<lgrid, 256, 0, stream>>>(
            xt, B[t & 1], B[(t + 1) & 1], c0, Wx0b, Wh0b, bias0,
            H[(t + 1) & 1], H[t & 1], c1, Wx1b, Wh1b, bias1,
            tf32, t, n);
    }

    // ---- graph encoder: gemm -> fused gather+LN(+ReLU) ----
    const int gblocks  = (n + 63) / 64;
    const int nwblocks = (n + 3) / 4;
    gemm_h_kernel<<<gblocks, 256, 0, stream>>>(temporal, Wg1, G1, n);
    gather_ln_kernel<true><<<nwblocks, 256, 0, stream>>>(
        G1, rowstart, counts, s_srt, w_srt, dinv, bg1, g1, be1, G3, n);
    gemm_h_kernel<<<gblocks, 256, 0, stream>>>(G3, Wg2, G1, n);
    gather_ln_kernel<false><<<nwblocks, 256, 0, stream>>>(
        G1, rowstart, counts, s_srt, w_srt, dinv, bg2, g2, be2, G2, n);

    // ---- predictor ----
    predictor_kernel<<<(n + 255) / 256, 256, 0, stream>>>(
        temporal, G2, Wp1, bp1, Wp2, bp2, out, n);
}

// Round 11
// 1756.608 us; speedup vs baseline: 4.4645x; 1.0027x over previous
//
#include <hip/hip_runtime.h>
#include <math.h>

#define Hdim 128
#define Fdim 32
#define Tdim 16

typedef short  bfrag8 __attribute__((ext_vector_type(8)));
typedef float  facc4  __attribute__((ext_vector_type(4)));
typedef unsigned short ushort_t;

__device__ __forceinline__ float sigf(float x) {
    return 1.0f / (1.0f + __expf(-x));
}
__device__ __forceinline__ float tanh_fast(float x) {
    x = fminf(fmaxf(x, -15.f), 15.f);
    float e = __expf(2.f * x);
    return (e - 1.f) / (e + 1.f);
}
__device__ __forceinline__ ushort_t f2bf(float f) {
    union { float f; unsigned u; } v; v.f = f;
    unsigned u = v.u;
    unsigned r = u + 0x7fffu + ((u >> 16) & 1u);   // RNE
    return (ushort_t)(r >> 16);
}

// async global->LDS, 16B per lane; LDS dest = wave-uniform base + lane*16
typedef __attribute__((address_space(3))) unsigned int lds_uint;
typedef __attribute__((address_space(1))) const unsigned int glob_uint;
__device__ __forceinline__ void gload_lds16(const ushort_t* g, ushort_t* l) {
    __builtin_amdgcn_global_load_lds((glob_uint*)g, (lds_uint*)l, 16, 0, 0);
}

// ---------------- f32 -> bf16 convert (weights) ----------------
__global__ __launch_bounds__(256)
void cvt_bf16_kernel(const float* __restrict__ in, ushort_t* __restrict__ out, int nelem) {
    int i = (blockIdx.x * 256 + threadIdx.x) * 4;
    if (i < nelem) {
        float4 v = *reinterpret_cast<const float4*>(in + i);
        out[i + 0] = f2bf(v.x); out[i + 1] = f2bf(v.y);
        out[i + 2] = f2bf(v.z); out[i + 3] = f2bf(v.w);
    }
}

__global__ __launch_bounds__(256)
void bias_add_kernel(const float* __restrict__ a, const float* __restrict__ b,
                     float* __restrict__ out, int n) {
    int i = blockIdx.x * 256 + threadIdx.x;
    if (i < n) out[i] = a[i] + b[i];
}

// ---------------- x (N,F,T) f32 -> xs (T,N,F) bf16 ----------------
__global__ __launch_bounds__(256)
void transpose_x_kernel(const float* __restrict__ x, ushort_t* __restrict__ xs, int nf) {
    int tid = blockIdx.x * 256 + threadIdx.x;  // over N*F
    if (tid >= nf) return;
    const float4* src = reinterpret_cast<const float4*>(x + (size_t)tid * Tdim);
    float4 a = src[0], b = src[1], c = src[2], d = src[3];
    float v[16] = {a.x,a.y,a.z,a.w, b.x,b.y,b.z,b.w, c.x,c.y,c.z,c.w, d.x,d.y,d.z,d.w};
    #pragma unroll
    for (int t = 0; t < Tdim; ++t) xs[(size_t)t * nf + tid] = f2bf(v[t]);
}

// fallback: extract slice t of x -> xt (N,F) bf16
__global__ __launch_bounds__(256)
void xslice_kernel(const float* __restrict__ x, ushort_t* __restrict__ xt, int t, int n) {
    int idx = blockIdx.x * 256 + threadIdx.x;
    if (idx < n * Fdim) {
        int node = idx >> 5, f = idx & 31;
        xt[idx] = f2bf(x[(size_t)node * (Fdim * Tdim) + f * Tdim + t]);
    }
}

// ---------------- MFMA LSTM step (async dbuf LDS staging, bank-swizzled) ----------------
// Block: 128 rows x 32 jj x 4 gates. 4 waves (2 row x 2 jj).
// LDS rows are 64B (32 bf16). Without swizzle a quarter-wave b128 read hits
// only 2 of 8 four-bank groups (8-way conflict, 2.6M SQ_LDS_BANK_CONFLICT).
// Fix (rule 21): linear LDS dest; XOR chunk with (row>>1)&3 on BOTH the
// global source (staging) and the fragment read -- same involution.
template<int KX>
__device__ __forceinline__
void get_iter(int gi, const ushort_t* xt, const ushort_t* h_in,
              const ushort_t* Wx, const ushort_t* Wh,
              const ushort_t*& Ap, const ushort_t*& Wp, int& Kp, int& k0)
{
    constexpr int itX = KX / 32;
    if (gi < itX) { Ap = xt;   Wp = Wx; Kp = KX;   k0 = gi * 32; }
    else          { Ap = h_in; Wp = Wh; Kp = Hdim; k0 = (gi - itX) * 32; }
}

template<int KX>
__device__ __forceinline__
void lstm_step_core(const ushort_t* __restrict__ xt, const ushort_t* __restrict__ h_in,
                    float* __restrict__ c_state,
                    const ushort_t* __restrict__ Wx, const ushort_t* __restrict__ Wh,
                    const float* __restrict__ bias,
                    ushort_t* __restrict__ h_out, float* __restrict__ h_f32,
                    ushort_t (*As)[4096], ushort_t (*Bs)[4096],
                    int n, int bx, int by)
{
    constexpr int NIT = KX / 32 + 4;
    const int tid  = threadIdx.x;
    const int lane = tid & 63;
    const int w    = tid >> 6;
    const int wr   = w >> 1, wc = w & 1;
    const int rb_blk = bx * 128;
    const int jb_blk = by * 32;
    const int rl   = lane & 15;          // row-in-frag (A) / col-in-frag (B,C)
    const int ks   = lane >> 4;          // k-slot
    const int sub  = lane >> 2;          // staging: row-in-16
    // swizzled source chunk: lane's LDS slot (row=lane>>2, chunk'=lane&3)
    // receives global chunk = chunk' ^ ((row>>1)&3) = (lane&3)^((lane>>3)&3)
    const int boff = (((lane & 3) ^ ((lane >> 3) & 3))) * 8;
    const int swr  = (rl >> 1) & 3;      // read-side chunk swizzle

    auto stage = [&](int gi, int b) {
        const ushort_t *Ap, *Wp; int Kp, k0;
        get_iter<KX>(gi, xt, h_in, Wx, Wh, Ap, Wp, Kp, k0);
        #pragma unroll
        for (int h = 0; h < 2; ++h) {
            const int r = w * 32 + h * 16 + sub;            // 0..127
            int growA = rb_blk + r; growA = growA < n ? growA : n - 1;
            gload_lds16(Ap + (size_t)growA * Kp + k0 + boff,
                        As[b] + (w * 32 + h * 16) * 32);
            const int g = r >> 5, j = r & 31;               // z-row -> (gate,jj)
            gload_lds16(Wp + (size_t)(g * Hdim + jb_blk + j) * Kp + k0 + boff,
                        Bs[b] + (w * 32 + h * 16) * 32);
        }
    };

    facc4 acc[4][4] = {};                // [row-frag m][gate]

    stage(0, 0);
    __syncthreads();
    #pragma unroll
    for (int gi = 0; gi < NIT; ++gi) {
        const int cur = gi & 1;
        if (gi + 1 < NIT) stage(gi + 1, cur ^ 1);
        bfrag8 bfr[4];
        #pragma unroll
        for (int g = 0; g < 4; ++g)
            bfr[g] = *reinterpret_cast<const bfrag8*>(
                Bs[cur] + ((g * 32 + wc * 16 + rl) * 32 + ((ks ^ swr) * 8)));
        #pragma unroll
        for (int m = 0; m < 4; ++m) {
            bfrag8 afr = *reinterpret_cast<const bfrag8*>(
                As[cur] + ((wr * 64 + m * 16 + rl) * 32 + ((ks ^ swr) * 8)));
            #pragma unroll
            for (int g = 0; g < 4; ++g)
                acc[m][g] = __builtin_amdgcn_mfma_f32_16x16x32_bf16(
                    afr, bfr[g], acc[m][g], 0, 0, 0);
        }
        __syncthreads();   // drains this iter's ds_reads AND next-iter staging
    }

    // epilogue: C layout col=lane&15, row=(lane>>4)*4+j  [m89-verified]
    const int rb = rb_blk + wr * 64;
    const int jj = jb_blk + wc * 16 + rl;
    const float bi = bias[jj];
    const float bf_ = bias[Hdim + jj];
    const float bg = bias[2 * Hdim + jj];
    const float bo = bias[3 * Hdim + jj];
    #pragma unroll
    for (int m = 0; m < 4; ++m) {
        #pragma unroll
        for (int j = 0; j < 4; ++j) {
            const int r = rb + m * 16 + ks * 4 + j;
            if (r < n) {
                const size_t idx = (size_t)r * Hdim + jj;
                const float zi = acc[m][0][j] + bi;
                const float zf = acc[m][1][j] + bf_;
                const float zg = acc[m][2][j] + bg;
                const float zo = acc[m][3][j] + bo;
                const float co = c_state[idx];
                const float cn = sigf(zf) * co + sigf(zi) * tanh_fast(zg);
                c_state[idx] = cn;
                const float h = sigf(zo) * tanh_fast(cn);
                h_out[idx] = f2bf(h);
                if (h_f32 != nullptr) h_f32[idx] = h;
            }
        }
    }
}

// Paired launch: z==0 -> layer0 step t (t<Tdim); z==1 -> layer1 step t-1 (t>=1).
__global__ __launch_bounds__(256)
void lstm_pair_kernel(const ushort_t* __restrict__ xt,
                      const ushort_t* __restrict__ h0_in, ushort_t* __restrict__ h0_out,
                      float* __restrict__ c0,
                      const ushort_t* __restrict__ Wx0, const ushort_t* __restrict__ Wh0,
                      const float* __restrict__ b0,
                      const ushort_t* __restrict__ h1_in, ushort_t* __restrict__ h1_out,
                      float* __restrict__ c1,
                      const ushort_t* __restrict__ Wx1, const ushort_t* __restrict__ Wh1,
                      const float* __restrict__ b1,
                      float* __restrict__ temporal_or_null, int t, int n)
{
    __shared__ ushort_t As[2][4096];
    __shared__ ushort_t Bs[2][4096];
    if (blockIdx.z == 0) {
        if (t >= Tdim) return;
        lstm_step_core<Fdim>(xt, h0_in, c0, Wx0, Wh0, b0, h0_out, nullptr,
                             As, Bs, n, blockIdx.x, blockIdx.y);
    } else {
        if (t == 0) return;
        lstm_step_core<Hdim>(h0_in, h1_in, c1, Wx1, Wh1, b1, h1_out, temporal_or_null,
                             As, Bs, n, blockIdx.x, blockIdx.y);
    }
}

// ---------------- plain GEMM: C[n x 128] = A[n x 128] @ B[128 x 128] ----------------
__global__ __launch_bounds__(256)
void gemm_h_kernel(const float* __restrict__ A, const float* __restrict__ B,
                   float* __restrict__ C, int n)
{
    __shared__ float As[32][68];
    __shared__ float Bs[32][128];
    const int tid = threadIdx.x;
    const int jx = tid & 31;
    const int ry = tid >> 5;
    const int rowbase = blockIdx.x * 64;
    float acc[8][4];
    #pragma unroll
    for (int r = 0; r < 8; ++r)
        #pragma unroll
        for (int q = 0; q < 4; ++q) acc[r][q] = 0.f;

    for (int k0 = 0; k0 < 128; k0 += 32) {
        {
            const int kq = tid & 7, row = tid >> 3;
            #pragma unroll
            for (int hh = 0; hh < 2; ++hh) {
                const int r = row + hh * 32;
                const int grow = rowbase + r;
                float4 v = make_float4(0.f, 0.f, 0.f, 0.f);
                if (grow < n) v = *reinterpret_cast<const float4*>(
                                    A + (size_t)grow * 128 + k0 + kq * 4);
                As[kq*4+0][r] = v.x; As[kq*4+1][r] = v.y;
                As[kq*4+2][r] = v.z; As[kq*4+3][r] = v.w;
            }
        }
        {
            const float4* src = reinterpret_cast<const float4*>(B + (size_t)k0 * 128);
            float4* dst = reinterpret_cast<float4*>(&Bs[0][0]);
            for (int i = tid; i < 1024; i += 256) dst[i] = src[i];
        }
        __syncthreads();
        #pragma unroll
        for (int k = 0; k < 32; ++k) {
            float a[8];
            float4 a0 = *reinterpret_cast<const float4*>(&As[k][ry * 8]);
            float4 a1 = *reinterpret_cast<const float4*>(&As[k][ry * 8 + 4]);
            a[0]=a0.x; a[1]=a0.y; a[2]=a0.z; a[3]=a0.w;
            a[4]=a1.x; a[5]=a1.y; a[6]=a1.z; a[7]=a1.w;
            const float b0 = Bs[k][jx], b1 = Bs[k][jx+32];
            const float b2 = Bs[k][jx+64], b3 = Bs[k][jx+96];
            #pragma unroll
            for (int r = 0; r < 8; ++r) {
                acc[r][0] = fmaf(a[r], b0, acc[r][0]);
                acc[r][1] = fmaf(a[r], b1, acc[r][1]);
                acc[r][2] = fmaf(a[r], b2, acc[r][2]);
                acc[r][3] = fmaf(a[r], b3, acc[r][3]);
            }
        }
        __syncthreads();
    }
    #pragma unroll
    for (int r = 0; r < 8; ++r) {
        const int grow = rowbase + ry * 8 + r;
        if (grow < n) {
            #pragma unroll
            for (int q = 0; q < 4; ++q)
                C[(size_t)grow * 128 + jx + q * 32] = acc[r][q];
        }
    }
}

// ---------------- CSR build ----------------
__global__ __launch_bounds__(256)
void deg_hist_kernel(const int* __restrict__ dst, const float* __restrict__ w,
                     float* deg, int* counts, int E) {
    int e = blockIdx.x * 256 + threadIdx.x;
    if (e < E) {
        int d = dst[e];
        atomicAdd(&deg[d], w[e]);
        atomicAdd(&counts[d], 1);
    }
}

__global__ __launch_bounds__(256)
void dinv_kernel(float* deg_dinv, int n) {
    int i = blockIdx.x * 256 + threadIdx.x;
    if (i < n) deg_dinv[i] = rsqrtf(deg_dinv[i] + 1.0f);  // +1 = self-loop
}

__global__ __launch_bounds__(256)
void scan1_kernel(const int* __restrict__ counts, int* __restrict__ Sloc,
                  int* __restrict__ bsum, int n) {
    __shared__ int tmp[256];
    const int i = blockIdx.x * 256 + threadIdx.x;
    tmp[threadIdx.x] = (i < n) ? counts[i] : 0;
    __syncthreads();
    #pragma unroll
    for (int off = 1; off < 256; off <<= 1) {
        int t = (threadIdx.x >= off) ? tmp[threadIdx.x - off] : 0;
        __syncthreads();
        tmp[threadIdx.x] += t;
        __syncthreads();
    }
    if (i < n) Sloc[i] = tmp[threadIdx.x];
    if (threadIdx.x == 255) bsum[blockIdx.x] = tmp[255];
}

__global__ __launch_bounds__(256)
void scan2_kernel(int* __restrict__ bsum, int nb) {
    __shared__ int tmp[256];
    tmp[threadIdx.x] = (threadIdx.x < nb) ? bsum[threadIdx.x] : 0;
    __syncthreads();
    #pragma unroll
    for (int off = 1; off < 256; off <<= 1) {
        int t = (threadIdx.x >= off) ? tmp[threadIdx.x - off] : 0;
        __syncthreads();
        tmp[threadIdx.x] += t;
        __syncthreads();
    }
    if (threadIdx.x < nb) bsum[threadIdx.x] = tmp[threadIdx.x];
}

__global__ __launch_bounds__(256)
void scan3_kernel(const int* __restrict__ Sloc, const int* __restrict__ bsum,
                  const int* __restrict__ counts,
                  int* __restrict__ rowstart, int* __restrict__ running, int n) {
    const int i = blockIdx.x * 256 + threadIdx.x;
    if (i >= n) return;
    const int S = Sloc[i] + (blockIdx.x > 0 ? bsum[blockIdx.x - 1] : 0);
    const int rs = S - counts[i];
    rowstart[i] = rs;
    running[i]  = rs;
}

__global__ __launch_bounds__(256)
void scatter_kernel(const int* __restrict__ src, const int* __restrict__ dst,
                    const float* __restrict__ w, const float* __restrict__ dinv,
                    int* __restrict__ running,
                    int* __restrict__ s_srt, float* __restrict__ w_srt, int E) {
    int e = blockIdx.x * 256 + threadIdx.x;
    if (e >= E) return;
    const int s = src[e], d = dst[e];
    const int pos = atomicAdd(&running[d], 1);
    s_srt[pos] = s;
    w_srt[pos] = dinv[s] * w[e] * dinv[d];
}

// ---------------- fused gather + bias + self-loop + LayerNorm (+ReLU) ----------------
template<bool RELU>
__global__ __launch_bounds__(256)
void gather_ln_kernel(const float* __restrict__ hlin,
                      const int* __restrict__ rowstart, const int* __restrict__ counts,
                      const int* __restrict__ s_srt, const float* __restrict__ w_srt,
                      const float* __restrict__ dinv, const float* __restrict__ bias,
                      const float* __restrict__ gamma, const float* __restrict__ beta,
                      float* __restrict__ out, int n)
{
    const int wave = threadIdx.x >> 6;
    const int lane = threadIdx.x & 63;
    const int node = blockIdx.x * 4 + wave;
    if (node >= n) return;

    const float di = dinv[node];
    float a0 = hlin[(size_t)node * Hdim + lane]      * di * di + bias[lane];
    float a1 = hlin[(size_t)node * Hdim + 64 + lane] * di * di + bias[64 + lane];

    const int rs  = rowstart[node];
    const int cnt = counts[node];
    int j = rs;
    const int jend = rs + cnt;
    for (; j + 1 < jend; j += 2) {
        const int   sA = s_srt[j],     sB = s_srt[j + 1];
        const float wA = w_srt[j],     wB = w_srt[j + 1];
        const float* rA = hlin + (size_t)sA * Hdim;
        const float* rB = hlin + (size_t)sB * Hdim;
        a0 += rA[lane] * wA;      a1 += rA[64 + lane] * wA;
        a0 += rB[lane] * wB;      a1 += rB[64 + lane] * wB;
    }
    if (j < jend) {
        const int   sA = s_srt[j];
        const float wA = w_srt[j];
        const float* rA = hlin + (size_t)sA * Hdim;
        a0 += rA[lane] * wA;      a1 += rA[64 + lane] * wA;
    }

    float s = a0 + a1;
    #pragma unroll
    for (int m = 32; m >= 1; m >>= 1) s += __shfl_xor(s, m);
    const float mu = s * (1.f / 128.f);
    const float d0 = a0 - mu, d1 = a1 - mu;
    float v = d0 * d0 + d1 * d1;
    #pragma unroll
    for (int m = 32; m >= 1; m >>= 1) v += __shfl_xor(v, m);
    const float rstd = rsqrtf(v * (1.f / 128.f) + 1e-5f);
    float y0 = d0 * rstd * gamma[lane]      + beta[lane];
    float y1 = d1 * rstd * gamma[64 + lane] + beta[64 + lane];
    if (RELU) { y0 = fmaxf(y0, 0.f); y1 = fmaxf(y1, 0.f); }
    out[(size_t)node * Hdim + lane]      = y0;
    out[(size_t)node * Hdim + 64 + lane] = y1;
}

// ---------------- predictor: thread-per-node, Wp1 staged in LDS ----------------
__global__ __launch_bounds__(256)
void predictor_kernel(const float* __restrict__ temporal, const float* __restrict__ gfeat,
                      const float* __restrict__ Wp1, const float* __restrict__ bp1,
                      const float* __restrict__ Wp2, const float* __restrict__ bp2,
                      float* __restrict__ out, int n)
{
    __shared__ float Ws[256 * 64];   // whole Wp1, 64 KiB
    const int tid = threadIdx.x;
    {
        const float4* src = reinterpret_cast<const float4*>(Wp1);
        float4* dst = reinterpret_cast<float4*>(Ws);
        for (int i = tid; i < 4096; i += 256) dst[i] = src[i];
    }
    __syncthreads();
    const int node = blockIdx.x * 256 + tid;
    const int nd = node < n ? node : n - 1;
    float acc[64];
    #pragma unroll
    for (int l = 0; l < 64; ++l) acc[l] = bp1[l];
    #pragma unroll
    for (int half = 0; half < 2; ++half) {
        const float* srcp = (half == 0 ? temporal : gfeat) + (size_t)nd * 128;
        #pragma unroll 4
        for (int k4 = 0; k4 < 32; ++k4) {
            const float4 f = reinterpret_cast<const float4*>(srcp)[k4];
            const float fe[4] = { f.x, f.y, f.z, f.w };
            #pragma unroll
            for (int e = 0; e < 4; ++e) {
                const float4* wrow = reinterpret_cast<const float4*>(
                    Ws + (half * 128 + k4 * 4 + e) * 64);
                #pragma unroll
                for (int l4 = 0; l4 < 16; ++l4) {
                    const float4 wv = wrow[l4];
                    acc[l4*4+0] = fmaf(fe[e], wv.x, acc[l4*4+0]);
                    acc[l4*4+1] = fmaf(fe[e], wv.y, acc[l4*4+1]);
                    acc[l4*4+2] = fmaf(fe[e], wv.z, acc[l4*4+2]);
                    acc[l4*4+3] = fmaf(fe[e], wv.w, acc[l4*4+3]);
                }
            }
        }
    }
    float p = bp2[0];
    #pragma unroll
    for (int l = 0; l < 64; ++l)
        p = fmaf(fmaxf(acc[l], 0.f), Wp2[l], p);
    if (node < n) out[node] = p;
}

extern "C" void kernel_launch(void* const* d_in, const int* in_sizes, int n_in,
                              void* d_out, int out_size, void* d_ws, size_t ws_size,
                              hipStream_t stream) {
    const float* x    = (const float*)d_in[0];
    const int*   ei   = (const int*)d_in[1];
    const float* ew   = (const float*)d_in[2];
    const float* Wih0 = (const float*)d_in[3];
    const float* Whh0 = (const float*)d_in[4];
    const float* bih0 = (const float*)d_in[5];
    const float* bhh0 = (const float*)d_in[6];
    const float* Wih1 = (const float*)d_in[7];
    const float* Whh1 = (const float*)d_in[8];
    const float* bih1 = (const float*)d_in[9];
    const float* bhh1 = (const float*)d_in[10];
    const float* Wg1  = (const float*)d_in[11];
    const float* bg1  = (const float*)d_in[12];
    const float* g1   = (const float*)d_in[13];
    const float* be1  = (const float*)d_in[14];
    const float* Wg2  = (const float*)d_in[15];
    const float* bg2  = (const float*)d_in[16];
    const float* g2   = (const float*)d_in[17];
    const float* be2  = (const float*)d_in[18];
    const float* Wp1  = (const float*)d_in[19];
    const float* bp1  = (const float*)d_in[20];
    const float* Wp2  = (const float*)d_in[21];
    const float* bp2  = (const float*)d_in[22];
    float* out = (float*)d_out;

    const int n = in_sizes[0] / (Fdim * Tdim);
    const int E = in_sizes[1] / 2;
    const int* esrc = ei;
    const int* edst = ei + E;

    const size_t NH = (size_t)n * Hdim;
    const size_t NF = (size_t)n * Fdim;

    // ---- workspace layout (byte bump-allocator, 256B aligned) ----
    const size_t wsz_weights = (size_t)(512 * Fdim + 3 * 512 * Hdim) * 2;
    const size_t csr_bytes = (size_t)n * 16 + (size_t)E * 8 + 2048;
    const size_t need_rest = 4 * (NH * 2)
                           + 2 * (NH * 4)
                           + (NH * 4)
                           + (size_t)n * 4
                           + wsz_weights + 2 * 512 * 4 + csr_bytes + 16384;
    const bool use_xs = ws_size >= NF * Tdim * 2 + need_rest;

    char* base = (char*)d_ws;
    size_t off = 0;
    auto alloc = [&](size_t bytes) -> char* {
        off = (off + 255) & ~(size_t)255;
        char* p = base + off;
        off += bytes;
        return p;
    };
    ushort_t* xs   = (ushort_t*)alloc(use_xs ? NF * Tdim * 2 : NF * 2);
    ushort_t* h0a  = (ushort_t*)alloc(NH * 2);
    ushort_t* h0b  = (ushort_t*)alloc(NH * 2);
    ushort_t* h1a  = (ushort_t*)alloc(NH * 2);
    ushort_t* h1b  = (ushort_t*)alloc(NH * 2);
    float*    c0   = (float*)alloc(NH * 4);
    float*    c1   = (float*)alloc(NH * 4);
    float*    temporal = (float*)alloc(NH * 4);
    float*    dinv = (float*)alloc((size_t)n * 4);
    ushort_t* Wx0b = (ushort_t*)alloc((size_t)512 * Fdim * 2);
    ushort_t* Wh0b = (ushort_t*)alloc((size_t)512 * Hdim * 2);
    ushort_t* Wx1b = (ushort_t*)alloc((size_t)512 * Hdim * 2);
    ushort_t* Wh1b = (ushort_t*)alloc((size_t)512 * Hdim * 2);
    float*    bias0 = (float*)alloc(512 * 4);
    float*    bias1 = (float*)alloc(512 * 4);
    int*   counts   = (int*)alloc((size_t)n * 4);
    int*   Sloc     = (int*)alloc((size_t)n * 4);
    int*   bsum     = (int*)alloc(1024);
    int*   rowstart = (int*)alloc((size_t)n * 4);
    int*   running  = (int*)alloc((size_t)n * 4);
    int*   s_srt    = (int*)alloc((size_t)E * 4);
    float* w_srt    = (float*)alloc((size_t)E * 4);
    // graph-phase scratch aliases the LSTM-dead region at the base
    float* G1 = (float*)base;
    float* G2 = G1 + NH;
    float* G3 = G2 + NH;

    // ---- weight/bias prep ----
    {
        const int n0 = 512 * Fdim, n1 = 512 * Hdim;
        cvt_bf16_kernel<<<(n0/4 + 255)/256, 256, 0, stream>>>(Wih0, Wx0b, n0);
        cvt_bf16_kernel<<<(n1/4 + 255)/256, 256, 0, stream>>>(Whh0, Wh0b, n1);
        cvt_bf16_kernel<<<(n1/4 + 255)/256, 256, 0, stream>>>(Wih1, Wx1b, n1);
        cvt_bf16_kernel<<<(n1/4 + 255)/256, 256, 0, stream>>>(Whh1, Wh1b, n1);
        bias_add_kernel<<<2, 256, 0, stream>>>(bih0, bhh0, bias0, 512);
        bias_add_kernel<<<2, 256, 0, stream>>>(bih1, bhh1, bias1, 512);
    }

    hipMemsetAsync(h0a, 0, NH * 2, stream);
    hipMemsetAsync(h1a, 0, NH * 2, stream);
    hipMemsetAsync(c0, 0, NH * 4, stream);
    hipMemsetAsync(c1, 0, NH * 4, stream);
    hipMemsetAsync(dinv, 0, (size_t)n * 4, stream);
    hipMemsetAsync(counts, 0, (size_t)n * 4, stream);

    // ---- CSR build (graph shared by both GCN layers) ----
    {
        const int eb = (E + 255) / 256;
        const int nb = (n + 255) / 256;
        deg_hist_kernel<<<eb, 256, 0, stream>>>(edst, ew, dinv, counts, E);
        dinv_kernel<<<nb, 256, 0, stream>>>(dinv, n);
        scan1_kernel<<<nb, 256, 0, stream>>>(counts, Sloc, bsum, n);
        scan2_kernel<<<1, 256, 0, stream>>>(bsum, nb);
        scan3_kernel<<<nb, 256, 0, stream>>>(Sloc, bsum, counts, rowstart, running, n);
        scatter_kernel<<<eb, 256, 0, stream>>>(esrc, edst, ew, dinv, running,
                                               s_srt, w_srt, E);
    }

    if (use_xs)
        transpose_x_kernel<<<(int)((NF + 255) / 256), 256, 0, stream>>>(x, xs, (int)NF);

    // ---- LSTM: 17 paired launches (L0 step t || L1 step t-1) ----
    ushort_t* B[2] = { h0a, h0b };
    ushort_t* H[2] = { h1a, h1b };
    dim3 lgrid((n + 127) / 128, 4, 2);
    for (int t = 0; t <= Tdim; ++t) {
        const ushort_t* xt = xs;
        if (t < Tdim) {
            if (use_xs) xt = xs + (size_t)t * NF;
            else {
                xslice_kernel<<<(int)((NF + 255) / 256), 256, 0, stream>>>(x, xs, t, n);
                xt = xs;
            }
        }
        float* tf32 = (t == Tdim) ? temporal : nullptr;
        lstm_pair_kernel<<<lgrid, 256, 0, stream>>>(
            xt, B[t & 1], B[(t + 1) & 1], c0, Wx0b, Wh0b, bias0,
            H[(t + 1) & 1], H[t & 1], c1, Wx1b, Wh1b, bias1,
            tf32, t, n);
    }

    // ---- graph encoder: gemm -> fused gather+LN(+ReLU) ----
    const int gblocks  = (n + 63) / 64;
    const int nwblocks = (n + 3) / 4;
    gemm_h_kernel<<<gblocks, 256, 0, stream>>>(temporal, Wg1, G1, n);
    gather_ln_kernel<true><<<nwblocks, 256, 0, stream>>>(
        G1, rowstart, counts, s_srt, w_srt, dinv, bg1, g1, be1, G3, n);
    gemm_h_kernel<<<gblocks, 256, 0, stream>>>(G3, Wg2, G1, n);
    gather_ln_kernel<false><<<nwblocks, 256, 0, stream>>>(
        G1, rowstart, counts, s_srt, w_srt, dinv, bg2, g2, be2, G2, n);

    // ---- predictor ----
    predictor_kernel<<<(n + 255) / 256, 256, 0, stream>>>(
        temporal, G2, Wp1, bp1, Wp2, bp2, out, n);
}

// Round 12
// 1748.689 us; speedup vs baseline: 4.4847x; 1.0045x over previous
//
#include <hip/hip_runtime.h>
#include <math.h>

#define Hdim 128
#define Fdim 32
#define Tdim 16

typedef short  bfrag8 __attribute__((ext_vector_type(8)));
typedef float  facc4  __attribute__((ext_vector_type(4)));
typedef unsigned short ushort_t;

__device__ __forceinline__ float sigf(float x) {
    return 1.0f / (1.0f + __expf(-x));
}
__device__ __forceinline__ float tanh_fast(float x) {
    x = fminf(fmaxf(x, -15.f), 15.f);
    float e = __expf(2.f * x);
    return (e - 1.f) / (e + 1.f);
}
__device__ __forceinline__ ushort_t f2bf(float f) {
    union { float f; unsigned u; } v; v.f = f;
    unsigned u = v.u;
    unsigned r = u + 0x7fffu + ((u >> 16) & 1u);   // RNE
    return (ushort_t)(r >> 16);
}

// async global->LDS, 16B per lane; LDS dest = wave-uniform base + lane*16
typedef __attribute__((address_space(3))) unsigned int lds_uint;
typedef __attribute__((address_space(1))) const unsigned int glob_uint;
__device__ __forceinline__ void gload_lds16(const ushort_t* g, ushort_t* l) {
    __builtin_amdgcn_global_load_lds((glob_uint*)g, (lds_uint*)l, 16, 0, 0);
}

// ---------------- f32 -> bf16 convert (weights) ----------------
__global__ __launch_bounds__(256)
void cvt_bf16_kernel(const float* __restrict__ in, ushort_t* __restrict__ out, int nelem) {
    int i = (blockIdx.x * 256 + threadIdx.x) * 4;
    if (i < nelem) {
        float4 v = *reinterpret_cast<const float4*>(in + i);
        out[i + 0] = f2bf(v.x); out[i + 1] = f2bf(v.y);
        out[i + 2] = f2bf(v.z); out[i + 3] = f2bf(v.w);
    }
}

__global__ __launch_bounds__(256)
void bias_add_kernel(const float* __restrict__ a, const float* __restrict__ b,
                     float* __restrict__ out, int n) {
    int i = blockIdx.x * 256 + threadIdx.x;
    if (i < n) out[i] = a[i] + b[i];
}

// ---------------- x (N,F,T) f32 -> xs (T,N,F) bf16 ----------------
__global__ __launch_bounds__(256)
void transpose_x_kernel(const float* __restrict__ x, ushort_t* __restrict__ xs, int nf) {
    int tid = blockIdx.x * 256 + threadIdx.x;  // over N*F
    if (tid >= nf) return;
    const float4* src = reinterpret_cast<const float4*>(x + (size_t)tid * Tdim);
    float4 a = src[0], b = src[1], c = src[2], d = src[3];
    float v[16] = {a.x,a.y,a.z,a.w, b.x,b.y,b.z,b.w, c.x,c.y,c.z,c.w, d.x,d.y,d.z,d.w};
    #pragma unroll
    for (int t = 0; t < Tdim; ++t) xs[(size_t)t * nf + tid] = f2bf(v[t]);
}

// fallback: extract slice t of x -> xt (N,F) bf16
__global__ __launch_bounds__(256)
void xslice_kernel(const float* __restrict__ x, ushort_t* __restrict__ xt, int t, int n) {
    int idx = blockIdx.x * 256 + threadIdx.x;
    if (idx < n * Fdim) {
        int node = idx >> 5, f = idx & 31;
        xt[idx] = f2bf(x[(size_t)node * (Fdim * Tdim) + f * Tdim + t]);
    }
}

// ---------------- MFMA LSTM step (3-buf counted-vmcnt pipeline) ----------------
// Block: 128 rows x 32 jj x 4 gates. 4 waves (2 row x 2 jj).
// The __syncthreads barrier-drain (compiler emits vmcnt(0) before s_barrier)
// was the bottleneck: ~2200cy per k-iter exposed latency [R11 counters].
// Fix: 3-buffer rotation; per iter exactly ONE raw s_barrier preceded by a
// COUNTED vmcnt (4 = one stage of 4 global_load_lds instrs still in flight).
// WAR-safe: stage(i+2)->buf[(i+2)%3] is issued after the barrier that all
// waves reach only after consuming buf[(i-1)%3] (same buffer) reads.
// Chunk XOR-swizzle retained from R11 (bank conflicts 0, bitwise-identical).
template<int KX>
__device__ __forceinline__
void get_iter(int gi, const ushort_t* xt, const ushort_t* h_in,
              const ushort_t* Wx, const ushort_t* Wh,
              const ushort_t*& Ap, const ushort_t*& Wp, int& Kp, int& k0)
{
    constexpr int itX = KX / 32;
    if (gi < itX) { Ap = xt;   Wp = Wx; Kp = KX;   k0 = gi * 32; }
    else          { Ap = h_in; Wp = Wh; Kp = Hdim; k0 = (gi - itX) * 32; }
}

template<int KX>
__device__ __forceinline__
void lstm_step_core(const ushort_t* __restrict__ xt, const ushort_t* __restrict__ h_in,
                    float* __restrict__ c_state,
                    const ushort_t* __restrict__ Wx, const ushort_t* __restrict__ Wh,
                    const float* __restrict__ bias,
                    ushort_t* __restrict__ h_out, float* __restrict__ h_f32,
                    ushort_t (*As)[4096], ushort_t (*Bs)[4096],
                    int n, int bx, int by)
{
    constexpr int NIT = KX / 32 + 4;
    const int tid  = threadIdx.x;
    const int lane = tid & 63;
    const int w    = tid >> 6;
    const int wr   = w >> 1, wc = w & 1;
    const int rb_blk = bx * 128;
    const int jb_blk = by * 32;
    const int rl   = lane & 15;          // row-in-frag (A) / col-in-frag (B,C)
    const int ks   = lane >> 4;          // k-slot
    const int sub  = lane >> 2;          // staging: row-in-16
    // swizzled source chunk (R11): lane's LDS slot (row=lane>>2, chunk'=lane&3)
    // receives global chunk = chunk' ^ ((row>>1)&3) = (lane&3)^((lane>>3)&3)
    const int boff = (((lane & 3) ^ ((lane >> 3) & 3))) * 8;
    const int swr  = (rl >> 1) & 3;      // read-side chunk swizzle

    auto stage = [&](int gi, int b) {
        const ushort_t *Ap, *Wp; int Kp, k0;
        get_iter<KX>(gi, xt, h_in, Wx, Wh, Ap, Wp, Kp, k0);
        #pragma unroll
        for (int h = 0; h < 2; ++h) {
            const int r = w * 32 + h * 16 + sub;            // 0..127
            int growA = rb_blk + r; growA = growA < n ? growA : n - 1;
            gload_lds16(Ap + (size_t)growA * Kp + k0 + boff,
                        As[b] + (w * 32 + h * 16) * 32);
            const int g = r >> 5, j = r & 31;               // z-row -> (gate,jj)
            gload_lds16(Wp + (size_t)(g * Hdim + jb_blk + j) * Kp + k0 + boff,
                        Bs[b] + (w * 32 + h * 16) * 32);
        }
    };

    facc4 acc[4][4] = {};                // [row-frag m][gate]

    stage(0, 0);
    stage(1, 1);
    #pragma unroll
    for (int gi = 0; gi < NIT; ++gi) {
        // --- counted-vmcnt raw barrier (ONE per iter) ---
        __builtin_amdgcn_sched_barrier(0);
        if (gi + 1 < NIT) asm volatile("s_waitcnt vmcnt(4)" ::: "memory");
        else              asm volatile("s_waitcnt vmcnt(0)" ::: "memory");
        __builtin_amdgcn_s_barrier();
        __builtin_amdgcn_sched_barrier(0);
        // prefetch two ahead into the buffer last read at iter gi-1
        if (gi + 2 < NIT) stage(gi + 2, (gi + 2) % 3);
        const int cur = gi % 3;
        bfrag8 bfr[4];
        #pragma unroll
        for (int g = 0; g < 4; ++g)
            bfr[g] = *reinterpret_cast<const bfrag8*>(
                Bs[cur] + ((g * 32 + wc * 16 + rl) * 32 + ((ks ^ swr) * 8)));
        #pragma unroll
        for (int m = 0; m < 4; ++m) {
            bfrag8 afr = *reinterpret_cast<const bfrag8*>(
                As[cur] + ((wr * 64 + m * 16 + rl) * 32 + ((ks ^ swr) * 8)));
            #pragma unroll
            for (int g = 0; g < 4; ++g)
                acc[m][g] = __builtin_amdgcn_mfma_f32_16x16x32_bf16(
                    afr, bfr[g], acc[m][g], 0, 0, 0);
        }
    }

    // epilogue: C layout col=lane&15, row=(lane>>4)*4+j  [m89-verified]
    const int rb = rb_blk + wr * 64;
    const int jj = jb_blk + wc * 16 + rl;
    const float bi = bias[jj];
    const float bf_ = bias[Hdim + jj];
    const float bg = bias[2 * Hdim + jj];
    const float bo = bias[3 * Hdim + jj];
    #pragma unroll
    for (int m = 0; m < 4; ++m) {
        #pragma unroll
        for (int j = 0; j < 4; ++j) {
            const int r = rb + m * 16 + ks * 4 + j;
            if (r < n) {
                const size_t idx = (size_t)r * Hdim + jj;
                const float zi = acc[m][0][j] + bi;
                const float zf = acc[m][1][j] + bf_;
                const float zg = acc[m][2][j] + bg;
                const float zo = acc[m][3][j] + bo;
                const float co = c_state[idx];
                const float cn = sigf(zf) * co + sigf(zi) * tanh_fast(zg);
                c_state[idx] = cn;
                const float h = sigf(zo) * tanh_fast(cn);
                h_out[idx] = f2bf(h);
                if (h_f32 != nullptr) h_f32[idx] = h;
            }
        }
    }
}

// Paired launch: z==0 -> layer0 step t (t<Tdim); z==1 -> layer1 step t-1 (t>=1).
__global__ __launch_bounds__(256)
void lstm_pair_kernel(const ushort_t* __restrict__ xt,
                      const ushort_t* __restrict__ h0_in, ushort_t* __restrict__ h0_out,
                      float* __restrict__ c0,
                      const ushort_t* __restrict__ Wx0, const ushort_t* __restrict__ Wh0,
                      const float* __restrict__ b0,
                      const ushort_t* __restrict__ h1_in, ushort_t* __restrict__ h1_out,
                      float* __restrict__ c1,
                      const ushort_t* __restrict__ Wx1, const ushort_t* __restrict__ Wh1,
                      const float* __restrict__ b1,
                      float* __restrict__ temporal_or_null, int t, int n)
{
    __shared__ ushort_t As[3][4096];
    __shared__ ushort_t Bs[3][4096];
    if (blockIdx.z == 0) {
        if (t >= Tdim) return;
        lstm_step_core<Fdim>(xt, h0_in, c0, Wx0, Wh0, b0, h0_out, nullptr,
                             As, Bs, n, blockIdx.x, blockIdx.y);
    } else {
        if (t == 0) return;
        lstm_step_core<Hdim>(h0_in, h1_in, c1, Wx1, Wh1, b1, h1_out, temporal_or_null,
                             As, Bs, n, blockIdx.x, blockIdx.y);
    }
}

// ---------------- plain GEMM: C[n x 128] = A[n x 128] @ B[128 x 128] ----------------
__global__ __launch_bounds__(256)
void gemm_h_kernel(const float* __restrict__ A, const float* __restrict__ B,
                   float* __restrict__ C, int n)
{
    __shared__ float As[32][68];
    __shared__ float Bs[32][128];
    const int tid = threadIdx.x;
    const int jx = tid & 31;
    const int ry = tid >> 5;
    const int rowbase = blockIdx.x * 64;
    float acc[8][4];
    #pragma unroll
    for (int r = 0; r < 8; ++r)
        #pragma unroll
        for (int q = 0; q < 4; ++q) acc[r][q] = 0.f;

    for (int k0 = 0; k0 < 128; k0 += 32) {
        {
            const int kq = tid & 7, row = tid >> 3;
            #pragma unroll
            for (int hh = 0; hh < 2; ++hh) {
                const int r = row + hh * 32;
                const int grow = rowbase + r;
                float4 v = make_float4(0.f, 0.f, 0.f, 0.f);
                if (grow < n) v = *reinterpret_cast<const float4*>(
                                    A + (size_t)grow * 128 + k0 + kq * 4);
                As[kq*4+0][r] = v.x; As[kq*4+1][r] = v.y;
                As[kq*4+2][r] = v.z; As[kq*4+3][r] = v.w;
            }
        }
        {
            const float4* src = reinterpret_cast<const float4*>(B + (size_t)k0 * 128);
            float4* dst = reinterpret_cast<float4*>(&Bs[0][0]);
            for (int i = tid; i < 1024; i += 256) dst[i] = src[i];
        }
        __syncthreads();
        #pragma unroll
        for (int k = 0; k < 32; ++k) {
            float a[8];
            float4 a0 = *reinterpret_cast<const float4*>(&As[k][ry * 8]);
            float4 a1 = *reinterpret_cast<const float4*>(&As[k][ry * 8 + 4]);
            a[0]=a0.x; a[1]=a0.y; a[2]=a0.z; a[3]=a0.w;
            a[4]=a1.x; a[5]=a1.y; a[6]=a1.z; a[7]=a1.w;
            const float b0 = Bs[k][jx], b1 = Bs[k][jx+32];
            const float b2 = Bs[k][jx+64], b3 = Bs[k][jx+96];
            #pragma unroll
            for (int r = 0; r < 8; ++r) {
                acc[r][0] = fmaf(a[r], b0, acc[r][0]);
                acc[r][1] = fmaf(a[r], b1, acc[r][1]);
                acc[r][2] = fmaf(a[r], b2, acc[r][2]);
                acc[r][3] = fmaf(a[r], b3, acc[r][3]);
            }
        }
        __syncthreads();
    }
    #pragma unroll
    for (int r = 0; r < 8; ++r) {
        const int grow = rowbase + ry * 8 + r;
        if (grow < n) {
            #pragma unroll
            for (int q = 0; q < 4; ++q)
                C[(size_t)grow * 128 + jx + q * 32] = acc[r][q];
        }
    }
}

// ---------------- CSR build ----------------
__global__ __launch_bounds__(256)
void deg_hist_kernel(const int* __restrict__ dst, const float* __restrict__ w,
                     float* deg, int* counts, int E) {
    int e = blockIdx.x * 256 + threadIdx.x;
    if (e < E) {
        int d = dst[e];
        atomicAdd(&deg[d], w[e]);
        atomicAdd(&counts[d], 1);
    }
}

__global__ __launch_bounds__(256)
void dinv_kernel(float* deg_dinv, int n) {
    int i = blockIdx.x * 256 + threadIdx.x;
    if (i < n) deg_dinv[i] = rsqrtf(deg_dinv[i] + 1.0f);  // +1 = self-loop
}

__global__ __launch_bounds__(256)
void scan1_kernel(const int* __restrict__ counts, int* __restrict__ Sloc,
                  int* __restrict__ bsum, int n) {
    __shared__ int tmp[256];
    const int i = blockIdx.x * 256 + threadIdx.x;
    tmp[threadIdx.x] = (i < n) ? counts[i] : 0;
    __syncthreads();
    #pragma unroll
    for (int off = 1; off < 256; off <<= 1) {
        int t = (threadIdx.x >= off) ? tmp[threadIdx.x - off] : 0;
        __syncthreads();
        tmp[threadIdx.x] += t;
        __syncthreads();
    }
    if (i < n) Sloc[i] = tmp[threadIdx.x];
    if (threadIdx.x == 255) bsum[blockIdx.x] = tmp[255];
}

__global__ __launch_bounds__(256)
void scan2_kernel(int* __restrict__ bsum, int nb) {
    __shared__ int tmp[256];
    tmp[threadIdx.x] = (threadIdx.x < nb) ? bsum[threadIdx.x] : 0;
    __syncthreads();
    #pragma unroll
    for (int off = 1; off < 256; off <<= 1) {
        int t = (threadIdx.x >= off) ? tmp[threadIdx.x - off] : 0;
        __syncthreads();
        tmp[threadIdx.x] += t;
        __syncthreads();
    }
    if (threadIdx.x < nb) bsum[threadIdx.x] = tmp[threadIdx.x];
}

__global__ __launch_bounds__(256)
void scan3_kernel(const int* __restrict__ Sloc, const int* __restrict__ bsum,
                  const int* __restrict__ counts,
                  int* __restrict__ rowstart, int* __restrict__ running, int n) {
    const int i = blockIdx.x * 256 + threadIdx.x;
    if (i >= n) return;
    const int S = Sloc[i] + (blockIdx.x > 0 ? bsum[blockIdx.x - 1] : 0);
    const int rs = S - counts[i];
    rowstart[i] = rs;
    running[i]  = rs;
}

__global__ __launch_bounds__(256)
void scatter_kernel(const int* __restrict__ src, const int* __restrict__ dst,
                    const float* __restrict__ w, const float* __restrict__ dinv,
                    int* __restrict__ running,
                    int* __restrict__ s_srt, float* __restrict__ w_srt, int E) {
    int e = blockIdx.x * 256 + threadIdx.x;
    if (e >= E) return;
    const int s = src[e], d = dst[e];
    const int pos = atomicAdd(&running[d], 1);
    s_srt[pos] = s;
    w_srt[pos] = dinv[s] * w[e] * dinv[d];
}

// ---------------- fused gather + bias + self-loop + LayerNorm (+ReLU) ----------------
template<bool RELU>
__global__ __launch_bounds__(256)
void gather_ln_kernel(const float* __restrict__ hlin,
                      const int* __restrict__ rowstart, const int* __restrict__ counts,
                      const int* __restrict__ s_srt, const float* __restrict__ w_srt,
                      const float* __restrict__ dinv, const float* __restrict__ bias,
                      const float* __restrict__ gamma, const float* __restrict__ beta,
                      float* __restrict__ out, int n)
{
    const int wave = threadIdx.x >> 6;
    const int lane = threadIdx.x & 63;
    const int node = blockIdx.x * 4 + wave;
    if (node >= n) return;

    const float di = dinv[node];
    float a0 = hlin[(size_t)node * Hdim + lane]      * di * di + bias[lane];
    float a1 = hlin[(size_t)node * Hdim + 64 + lane] * di * di + bias[64 + lane];

    const int rs  = rowstart[node];
    const int cnt = counts[node];
    int j = rs;
    const int jend = rs + cnt;
    for (; j + 1 < jend; j += 2) {
        const int   sA = s_srt[j],     sB = s_srt[j + 1];
        const float wA = w_srt[j],     wB = w_srt[j + 1];
        const float* rA = hlin + (size_t)sA * Hdim;
        const float* rB = hlin + (size_t)sB * Hdim;
        a0 += rA[lane] * wA;      a1 += rA[64 + lane] * wA;
        a0 += rB[lane] * wB;      a1 += rB[64 + lane] * wB;
    }
    if (j < jend) {
        const int   sA = s_srt[j];
        const float wA = w_srt[j];
        const float* rA = hlin + (size_t)sA * Hdim;
        a0 += rA[lane] * wA;      a1 += rA[64 + lane] * wA;
    }

    float s = a0 + a1;
    #pragma unroll
    for (int m = 32; m >= 1; m >>= 1) s += __shfl_xor(s, m);
    const float mu = s * (1.f / 128.f);
    const float d0 = a0 - mu, d1 = a1 - mu;
    float v = d0 * d0 + d1 * d1;
    #pragma unroll
    for (int m = 32; m >= 1; m >>= 1) v += __shfl_xor(v, m);
    const float rstd = rsqrtf(v * (1.f / 128.f) + 1e-5f);
    float y0 = d0 * rstd * gamma[lane]      + beta[lane];
    float y1 = d1 * rstd * gamma[64 + lane] + beta[64 + lane];
    if (RELU) { y0 = fmaxf(y0, 0.f); y1 = fmaxf(y1, 0.f); }
    out[(size_t)node * Hdim + lane]      = y0;
    out[(size_t)node * Hdim + 64 + lane] = y1;
}

// ---------------- predictor: thread-per-node, Wp1 staged in LDS ----------------
__global__ __launch_bounds__(256)
void predictor_kernel(const float* __restrict__ temporal, const float* __restrict__ gfeat,
                      const float* __restrict__ Wp1, const float* __restrict__ bp1,
                      const float* __restrict__ Wp2, const float* __restrict__ bp2,
                      float* __restrict__ out, int n)
{
    __shared__ float Ws[256 * 64];   // whole Wp1, 64 KiB
    const int tid = threadIdx.x;
    {
        const float4* src = reinterpret_cast<const float4*>(Wp1);
        float4* dst = reinterpret_cast<float4*>(Ws);
        for (int i = tid; i < 4096; i += 256) dst[i] = src[i];
    }
    __syncthreads();
    const int node = blockIdx.x * 256 + tid;
    const int nd = node < n ? node : n - 1;
    float acc[64];
    #pragma unroll
    for (int l = 0; l < 64; ++l) acc[l] = bp1[l];
    #pragma unroll
    for (int half = 0; half < 2; ++half) {
        const float* srcp = (half == 0 ? temporal : gfeat) + (size_t)nd * 128;
        #pragma unroll 4
        for (int k4 = 0; k4 < 32; ++k4) {
            const float4 f = reinterpret_cast<const float4*>(srcp)[k4];
            const float fe[4] = { f.x, f.y, f.z, f.w };
            #pragma unroll
            for (int e = 0; e < 4; ++e) {
                const float4* wrow = reinterpret_cast<const float4*>(
                    Ws + (half * 128 + k4 * 4 + e) * 64);
                #pragma unroll
                for (int l4 = 0; l4 < 16; ++l4) {
                    const float4 wv = wrow[l4];
                    acc[l4*4+0] = fmaf(fe[e], wv.x, acc[l4*4+0]);
                    acc[l4*4+1] = fmaf(fe[e], wv.y, acc[l4*4+1]);
                    acc[l4*4+2] = fmaf(fe[e], wv.z, acc[l4*4+2]);
                    acc[l4*4+3] = fmaf(fe[e], wv.w, acc[l4*4+3]);
                }
            }
        }
    }
    float p = bp2[0];
    #pragma unroll
    for (int l = 0; l < 64; ++l)
        p = fmaf(fmaxf(acc[l], 0.f), Wp2[l], p);
    if (node < n) out[node] = p;
}

extern "C" void kernel_launch(void* const* d_in, const int* in_sizes, int n_in,
                              void* d_out, int out_size, void* d_ws, size_t ws_size,
                              hipStream_t stream) {
    const float* x    = (const float*)d_in[0];
    const int*   ei   = (const int*)d_in[1];
    const float* ew   = (const float*)d_in[2];
    const float* Wih0 = (const float*)d_in[3];
    const float* Whh0 = (const float*)d_in[4];
    const float* bih0 = (const float*)d_in[5];
    const float* bhh0 = (const float*)d_in[6];
    const float* Wih1 = (const float*)d_in[7];
    const float* Whh1 = (const float*)d_in[8];
    const float* bih1 = (const float*)d_in[9];
    const float* bhh1 = (const float*)d_in[10];
    const float* Wg1  = (const float*)d_in[11];
    const float* bg1  = (const float*)d_in[12];
    const float* g1   = (const float*)d_in[13];
    const float* be1  = (const float*)d_in[14];
    const float* Wg2  = (const float*)d_in[15];
    const float* bg2  = (const float*)d_in[16];
    const float* g2   = (const float*)d_in[17];
    const float* be2  = (const float*)d_in[18];
    const float* Wp1  = (const float*)d_in[19];
    const float* bp1  = (const float*)d_in[20];
    const float* Wp2  = (const float*)d_in[21];
    const float* bp2  = (const float*)d_in[22];
    float* out = (float*)d_out;

    const int n = in_sizes[0] / (Fdim * Tdim);
    const int E = in_sizes[1] / 2;
    const int* esrc = ei;
    const int* edst = ei + E;

    const size_t NH = (size_t)n * Hdim;
    const size_t NF = (size_t)n * Fdim;

    // ---- workspace layout (byte bump-allocator, 256B aligned) ----
    const size_t wsz_weights = (size_t)(512 * Fdim + 3 * 512 * Hdim) * 2;
    const size_t csr_bytes = (size_t)n * 16 + (size_t)E * 8 + 2048;
    const size_t need_rest = 4 * (NH * 2)
                           + 2 * (NH * 4)
                           + (NH * 4)
                           + (size_t)n * 4
                           + wsz_weights + 2 * 512 * 4 + csr_bytes + 16384;
    const bool use_xs = ws_size >= NF * Tdim * 2 + need_rest;

    char* base = (char*)d_ws;
    size_t off = 0;
    auto alloc = [&](size_t bytes) -> char* {
        off = (off + 255) & ~(size_t)255;
        char* p = base + off;
        off += bytes;
        return p;
    };
    ushort_t* xs   = (ushort_t*)alloc(use_xs ? NF * Tdim * 2 : NF * 2);
    ushort_t* h0a  = (ushort_t*)alloc(NH * 2);
    ushort_t* h0b  = (ushort_t*)alloc(NH * 2);
    ushort_t* h1a  = (ushort_t*)alloc(NH * 2);
    ushort_t* h1b  = (ushort_t*)alloc(NH * 2);
    float*    c0   = (float*)alloc(NH * 4);
    float*    c1   = (float*)alloc(NH * 4);
    float*    temporal = (float*)alloc(NH * 4);
    float*    dinv = (float*)alloc((size_t)n * 4);
    ushort_t* Wx0b = (ushort_t*)alloc((size_t)512 * Fdim * 2);
    ushort_t* Wh0b = (ushort_t*)alloc((size_t)512 * Hdim * 2);
    ushort_t* Wx1b = (ushort_t*)alloc((size_t)512 * Hdim * 2);
    ushort_t* Wh1b = (ushort_t*)alloc((size_t)512 * Hdim * 2);
    float*    bias0 = (float*)alloc(512 * 4);
    float*    bias1 = (float*)alloc(512 * 4);
    int*   counts   = (int*)alloc((size_t)n * 4);
    int*   Sloc     = (int*)alloc((size_t)n * 4);
    int*   bsum     = (int*)alloc(1024);
    int*   rowstart = (int*)alloc((size_t)n * 4);
    int*   running  = (int*)alloc((size_t)n * 4);
    int*   s_srt    = (int*)alloc((size_t)E * 4);
    float* w_srt    = (float*)alloc((size_t)E * 4);
    // graph-phase scratch aliases the LSTM-dead region at the base
    float* G1 = (float*)base;
    float* G2 = G1 + NH;
    float* G3 = G2 + NH;

    // ---- weight/bias prep ----
    {
        const int n0 = 512 * Fdim, n1 = 512 * Hdim;
        cvt_bf16_kernel<<<(n0/4 + 255)/256, 256, 0, stream>>>(Wih0, Wx0b, n0);
        cvt_bf16_kernel<<<(n1/4 + 255)/256, 256, 0, stream>>>(Whh0, Wh0b, n1);
        cvt_bf16_kernel<<<(n1/4 + 255)/256, 256, 0, stream>>>(Wih1, Wx1b, n1);
        cvt_bf16_kernel<<<(n1/4 + 255)/256, 256, 0, stream>>>(Whh1, Wh1b, n1);
        bias_add_kernel<<<2, 256, 0, stream>>>(bih0, bhh0, bias0, 512);
        bias_add_kernel<<<2, 256, 0, stream>>>(bih1, bhh1, bias1, 512);
    }

    hipMemsetAsync(h0a, 0, NH * 2, stream);
    hipMemsetAsync(h1a, 0, NH * 2, stream);
    hipMemsetAsync(c0, 0, NH * 4, stream);
    hipMemsetAsync(c1, 0, NH * 4, stream);
    hipMemsetAsync(dinv, 0, (size_t)n * 4, stream);
    hipMemsetAsync(counts, 0, (size_t)n * 4, stream);

    // ---- CSR build (graph shared by both GCN layers) ----
    {
        const int eb = (E + 255) / 256;
        const int nb = (n + 255) / 256;
        deg_hist_kernel<<<eb, 256, 0, stream>>>(edst, ew, dinv, counts, E);
        dinv_kernel<<<nb, 256, 0, stream>>>(dinv, n);
        scan1_kernel<<<nb, 256, 0, stream>>>(counts, Sloc, bsum, n);
        scan2_kernel<<<1, 256, 0, stream>>>(bsum, nb);
        scan3_kernel<<<nb, 256, 0, stream>>>(Sloc, bsum, counts, rowstart, running, n);
        scatter_kernel<<<eb, 256, 0, stream>>>(esrc, edst, ew, dinv, running,
                                               s_srt, w_srt, E);
    }

    if (use_xs)
        transpose_x_kernel<<<(int)((NF + 255) / 256), 256, 0, stream>>>(x, xs, (int)NF);

    // ---- LSTM: 17 paired launches (L0 step t || L1 step t-1) ----
    ushort_t* B[2] = { h0a, h0b };
    ushort_t* H[2] = { h1a, h1b };
    dim3 lgrid((n + 127) / 128, 4, 2);
    for (int t = 0; t <= Tdim; ++t) {
        const ushort_t* xt = xs;
        if (t < Tdim) {
            if (use_xs) xt = xs + (size_t)t * NF;
            else {
                xslice_kernel<<<(int)((NF + 255) / 256), 256, 0, stream>>>(x, xs, t, n);
                xt = xs;
            }
        }
        float* tf32 = (t == Tdim) ? temporal : nullptr;
        lstm_pair_kernel<<<lgrid, 256, 0, stream>>>(
            xt, B[t & 1], B[(t + 1) & 1], c0, Wx0b, Wh0b, bias0,
            H[(t + 1) & 1], H[t & 1], c1, Wx1b, Wh1b, bias1,
            tf32, t, n);
    }

    // ---- graph encoder: gemm -> fused gather+LN(+ReLU) ----
    const int gblocks  = (n + 63) / 64;
    const int nwblocks = (n + 3) / 4;
    gemm_h_kernel<<<gblocks, 256, 0, stream>>>(temporal, Wg1, G1, n);
    gather_ln_kernel<true><<<nwblocks, 256, 0, stream>>>(
        G1, rowstart, counts, s_srt, w_srt, dinv, bg1, g1, be1, G3, n);
    gemm_h_kernel<<<gblocks, 256, 0, stream>>>(G3, Wg2, G1, n);
    gather_ln_kernel<false><<<nwblocks, 256, 0, stream>>>(
        G1, rowstart, counts, s_srt, w_srt, dinv, bg2, g2, be2, G2, n);

    // ---- predictor ----
    predictor_kernel<<<(n + 255) / 256, 256, 0, stream>>>(
        temporal, G2, Wp1, bp1, Wp2, bp2, out, n);
}